// Round 3
// baseline (809.942 us; speedup 1.0000x reference)
//
#include <hip/hip_runtime.h>
#include <hip/hip_bf16.h>
#include <math.h>

#define NA 50000
#define NE 800000
#define NG 64

#define NBIN 50176            // NA rounded up to 98*512, zero-padded
#define NCH 98                // scan chunks of 512
#define DPB 16                // dsts per block in edge_csr
#define SACC_P 132            // padded LDS acc row stride (words)

typedef float f32x4 __attribute__((ext_vector_type(4)));
typedef __bf16 bf16x8 __attribute__((ext_vector_type(8)));

__device__ __forceinline__ float ssp(float x) {
    float sp = (x > 15.0f) ? x : log1pf(__expf(x));
    return sp - 0.69314718f;
}

// ---------------------------------------------------------------------------
// CSR build: histogram -> 3-phase exclusive scan -> scatter permutation
// ---------------------------------------------------------------------------
__global__ __launch_bounds__(256) void hist_kernel(const int* __restrict__ a,
                                                   int* __restrict__ counts) {
    for (int i = blockIdx.x * 256 + threadIdx.x; i < NE; i += gridDim.x * 256)
        atomicAdd(&counts[a[2 * i]], 1);
}

__global__ __launch_bounds__(512) void scanA(const int* __restrict__ counts,
                                             int* __restrict__ chunk_sums) {
    __shared__ int red[512];
    int t = threadIdx.x;
    red[t] = counts[blockIdx.x * 512 + t];
    __syncthreads();
    for (int off = 256; off > 0; off >>= 1) {
        if (t < off) red[t] += red[t + off];
        __syncthreads();
    }
    if (t == 0) chunk_sums[blockIdx.x] = red[0];
}

__global__ __launch_bounds__(128) void scanB(int* __restrict__ chunk_sums) {
    __shared__ int s[128];
    int t = threadIdx.x;
    int v = (t < NCH) ? chunk_sums[t] : 0;
    s[t] = v;
    __syncthreads();
    for (int off = 1; off < 128; off <<= 1) {
        int add = (t >= off) ? s[t - off] : 0;
        __syncthreads();
        s[t] += add;
        __syncthreads();
    }
    if (t < NCH) chunk_sums[t] = s[t] - v;   // exclusive
}

__global__ __launch_bounds__(512) void scanC(const int* __restrict__ counts,
                                             const int* __restrict__ chunk_sums,
                                             int* __restrict__ row_ptr,
                                             int* __restrict__ cursor) {
    __shared__ int s[512];
    int t = threadIdx.x;
    int i = blockIdx.x * 512 + t;
    int v = counts[i];
    s[t] = v;
    __syncthreads();
    for (int off = 1; off < 512; off <<= 1) {
        int add = (t >= off) ? s[t - off] : 0;
        __syncthreads();
        s[t] += add;
        __syncthreads();
    }
    int excl = s[t] - v + chunk_sums[blockIdx.x];
    row_ptr[i] = excl;
    cursor[i]  = excl;
}

__global__ __launch_bounds__(256) void scatter_kernel(const int* __restrict__ a,
                                                      const float* __restrict__ e,
                                                      int* __restrict__ cursor,
                                                      float* __restrict__ sorted_e,
                                                      int* __restrict__ sorted_src) {
    for (int i = blockIdx.x * 256 + threadIdx.x; i < NE; i += gridDim.x * 256) {
        int dst = a[2 * i];
        int src = a[2 * i + 1];
        int pos = atomicAdd(&cursor[dst], 1);
        sorted_e[pos]   = e[i];
        sorted_src[pos] = src;
    }
}

// ---------------------------------------------------------------------------
// Fused edge pipeline over CSR: each block owns DPB dsts exclusively.
// Chunks of 128 sorted edges: gaussian A-frags -> MFMA filter (hi/lo bf16)
// -> gather rf[src] -> modulate -> LDS accumulate -> one plain store per dst.
// ---------------------------------------------------------------------------
__global__ __launch_bounds__(256) void edge_csr(const float* __restrict__ sorted_e,
                                                const int* __restrict__ sorted_src,
                                                const int* __restrict__ row_ptr,
                                                const float* __restrict__ Wf2,
                                                const float* __restrict__ bf2,
                                                const float* __restrict__ rf,
                                                float* __restrict__ seg) {
    __shared__ __bf16 sWhi[128 * 64];       // Wf2^T hi, [n][k], k8 XOR swizzle
    __shared__ __bf16 sWlo[128 * 64];
    __shared__ float  sacc[DPB * SACC_P];   // per-dst accumulator, padded
    __shared__ float  sse[128];
    __shared__ int    sssrc[128], sdl[128];
    __shared__ int    srp[DPB + 1];

    const int tid = threadIdx.x;

    for (int i = tid; i < 64 * 128; i += 256) {
        int k = i >> 7, n = i & 127;
        float v = Wf2[i];
        __bf16 h = (__bf16)v;
        __bf16 l = (__bf16)(v - (float)h);
        int addr = n * 64 + (((k >> 3) ^ (n & 7)) << 3) + (k & 7);
        sWhi[addr] = h;
        sWlo[addr] = l;
    }
    for (int i = tid; i < DPB * SACC_P; i += 256) sacc[i] = 0.0f;
    const int d0 = blockIdx.x * DPB;
    if (tid <= DPB) srp[tid] = row_ptr[d0 + tid];
    __syncthreads();

    const int lane = tid & 63, w = tid >> 6;
    const int lrow = lane & 15, lgrp = lane >> 4;
    const float coeff = -0.5f * (63.0f / 5.0f) * (63.0f / 5.0f);

    float bv[8];
    #pragma unroll
    for (int nt = 0; nt < 8; ++nt) bv[nt] = bf2[nt * 16 + lrow];

    const int e0 = srp[0], e1 = srp[DPB];

    for (int p0 = e0; p0 < e1; p0 += 128) {
        __syncthreads();   // previous chunk's LDS reads/atomics done
        if (tid < 128) {
            int idx = p0 + tid;
            bool valid = idx < e1;
            sse[tid]   = valid ? sorted_e[idx] : 0.0f;
            sssrc[tid] = valid ? sorted_src[idx] : 0;
            int ld = 0;
            if (valid) {
                #pragma unroll
                for (int j = 1; j < DPB; ++j) ld += (idx >= srp[j]);
            } else ld = -1;
            sdl[tid] = ld;
        }
        __syncthreads();

        // A fragments for this wave's 32 edges (2 M-tiles of 16)
        bf16x8 ah[2][2], al[2][2];
        #pragma unroll
        for (int mt = 0; mt < 2; ++mt) {
            float ev = sse[w * 32 + mt * 16 + lrow];
            #pragma unroll
            for (int ks = 0; ks < 2; ++ks) {
                #pragma unroll
                for (int j = 0; j < 8; ++j) {
                    int k = ks * 32 + lgrp * 8 + j;
                    float d = ev - (5.0f / 63.0f) * (float)k;
                    float g = __expf(coeff * d * d);
                    __bf16 h = (__bf16)g;
                    ah[mt][ks][j] = h;
                    al[mt][ks][j] = (__bf16)(g - (float)h);
                }
            }
        }

        f32x4 acc[2][8];
        #pragma unroll
        for (int mt = 0; mt < 2; ++mt)
            #pragma unroll
            for (int nt = 0; nt < 8; ++nt)
                acc[mt][nt] = (f32x4){0.f, 0.f, 0.f, 0.f};

        #pragma unroll
        for (int ks = 0; ks < 2; ++ks) {
            #pragma unroll
            for (int nt = 0; nt < 8; ++nt) {
                int n = nt * 16 + lrow;
                int k8 = ks * 4 + lgrp;
                int addr = n * 64 + ((k8 ^ (n & 7)) << 3);
                bf16x8 bh = *(const bf16x8*)&sWhi[addr];
                bf16x8 bl = *(const bf16x8*)&sWlo[addr];
                #pragma unroll
                for (int mt = 0; mt < 2; ++mt) {
                    acc[mt][nt] = __builtin_amdgcn_mfma_f32_16x16x32_bf16(ah[mt][ks], bh, acc[mt][nt], 0, 0, 0);
                    acc[mt][nt] = __builtin_amdgcn_mfma_f32_16x16x32_bf16(ah[mt][ks], bl, acc[mt][nt], 0, 0, 0);
                    acc[mt][nt] = __builtin_amdgcn_mfma_f32_16x16x32_bf16(al[mt][ks], bh, acc[mt][nt], 0, 0, 0);
                }
            }
        }

        // gather + modulate + LDS accumulate
        #pragma unroll
        for (int mt = 0; mt < 2; ++mt) {
            #pragma unroll
            for (int r = 0; r < 4; ++r) {
                int el = w * 32 + mt * 16 + lgrp * 4 + r;
                int ld = sdl[el];
                if (ld >= 0) {
                    int src = sssrc[el];
                    const float* rfp = rf + (size_t)src * 128 + lrow;
                    float* ap = &sacc[ld * SACC_P + lrow];
                    #pragma unroll
                    for (int nt = 0; nt < 8; ++nt) {
                        float wv = acc[mt][nt][r] + bv[nt];
                        atomicAdd(&ap[nt * 16], rfp[nt * 16] * wv);
                    }
                }
            }
        }
    }
    __syncthreads();

    // write DPB complete rows with plain stores
    {
        int row = tid >> 4;               // 0..15
        int cb  = (tid & 15) * 8;         // 0..120
        const float* sp = &sacc[row * SACC_P + cb];
        float4 v0 = *(const float4*)&sp[0];
        float4 v1 = *(const float4*)&sp[4];
        float* op = &seg[(size_t)(d0 + row) * 128 + cb];
        *(float4*)&op[0] = v0;
        *(float4*)&op[4] = v1;
    }
}

// ---------------------------------------------------------------------------
// Dense GEMM: C[M,128] = act(A[M,128] @ W[128,128] + b), hi/lo split MFMA.
// ---------------------------------------------------------------------------
template<int ACT, int BIAS>
__global__ __launch_bounds__(256) void mfma_gemm(const float* __restrict__ A,
                                                 const float* __restrict__ W,
                                                 const float* __restrict__ b,
                                                 float* __restrict__ C, int M) {
    __shared__ __bf16 sWhi[128 * 128];
    __shared__ __bf16 sWlo[128 * 128];

    const int tid = threadIdx.x;
    for (int i = tid; i < 128 * 128; i += 256) {
        int k = i >> 7, n = i & 127;
        float v = W[i];
        __bf16 h = (__bf16)v;
        __bf16 l = (__bf16)(v - (float)h);
        int addr = n * 128 + (((k >> 3) ^ (n & 15)) << 3) + (k & 7);
        sWhi[addr] = h;
        sWlo[addr] = l;
    }
    __syncthreads();

    const int lane = tid & 63, w = tid >> 6;
    const int lrow = lane & 15, lgrp = lane >> 4;

    float bv[8];
    #pragma unroll
    for (int nt = 0; nt < 8; ++nt) bv[nt] = BIAS ? b[nt * 16 + lrow] : 0.0f;

    const int row  = blockIdx.x * 64 + w * 16 + lrow;
    const int rowc = row < M ? row : M - 1;

    f32x4 acc[8];
    #pragma unroll
    for (int nt = 0; nt < 8; ++nt) acc[nt] = (f32x4){0.f, 0.f, 0.f, 0.f};

    #pragma unroll
    for (int ks = 0; ks < 4; ++ks) {
        int k0 = ks * 32 + lgrp * 8;
        float4 f0 = *(const float4*)&A[(size_t)rowc * 128 + k0];
        float4 f1 = *(const float4*)&A[(size_t)rowc * 128 + k0 + 4];
        float av[8] = {f0.x, f0.y, f0.z, f0.w, f1.x, f1.y, f1.z, f1.w};
        bf16x8 ah, al;
        #pragma unroll
        for (int j = 0; j < 8; ++j) {
            __bf16 h = (__bf16)av[j];
            ah[j] = h;
            al[j] = (__bf16)(av[j] - (float)h);
        }
        #pragma unroll
        for (int nt = 0; nt < 8; ++nt) {
            int n = nt * 16 + lrow;
            int k8 = ks * 4 + lgrp;
            int addr = n * 128 + ((k8 ^ (n & 15)) << 3);
            bf16x8 bh = *(const bf16x8*)&sWhi[addr];
            bf16x8 bl = *(const bf16x8*)&sWlo[addr];
            acc[nt] = __builtin_amdgcn_mfma_f32_16x16x32_bf16(ah, bh, acc[nt], 0, 0, 0);
            acc[nt] = __builtin_amdgcn_mfma_f32_16x16x32_bf16(ah, bl, acc[nt], 0, 0, 0);
            acc[nt] = __builtin_amdgcn_mfma_f32_16x16x32_bf16(al, bh, acc[nt], 0, 0, 0);
        }
    }

    const int orow = blockIdx.x * 64 + w * 16 + lgrp * 4;
    #pragma unroll
    for (int r = 0; r < 4; ++r) {
        if (orow + r < M) {
            #pragma unroll
            for (int nt = 0; nt < 8; ++nt) {
                float v = acc[nt][r] + bv[nt];
                if (ACT) v = ssp(v);
                C[(size_t)(orow + r) * 128 + nt * 16 + lrow] = v;
            }
        }
    }
}

extern "C" void kernel_launch(void* const* d_in, const int* in_sizes, int n_in,
                              void* d_out, int out_size, void* d_ws, size_t ws_size,
                              hipStream_t stream) {
    const float* r   = (const float*)d_in[0];
    const float* e   = (const float*)d_in[1];
    const float* Wf2 = (const float*)d_in[2];
    const float* bf2 = (const float*)d_in[3];
    const float* Wa  = (const float*)d_in[4];
    const float* W1  = (const float*)d_in[5];
    const float* b1  = (const float*)d_in[6];
    const float* W2  = (const float*)d_in[7];
    const float* b2  = (const float*)d_in[8];
    const int*   a   = (const int*)d_in[9];

    float* out = (float*)d_out;

    // workspace layout (4B words)
    float* buf0       = (float*)d_ws;                 // rf / y1   (6.4M words)
    int*   counts     = (int*)d_ws + 6400000;         // NBIN
    int*   row_ptr    = counts + NBIN;                // NBIN
    int*   cursor     = row_ptr + NBIN;               // NBIN
    int*   chunk_sums = cursor + NBIN;                // 128
    float* sorted_e   = (float*)(chunk_sums + 128);   // NE
    int*   sorted_src = (int*)(sorted_e + NE);        // NE

    float* seg = out;   // d_out doubles as segment-sum buffer

    // --- CSR build ---
    hipMemsetAsync(counts, 0, NBIN * sizeof(int), stream);
    hist_kernel<<<1024, 256, 0, stream>>>(a, counts);
    scanA<<<NCH, 512, 0, stream>>>(counts, chunk_sums);
    scanB<<<1, 128, 0, stream>>>(chunk_sums);
    scanC<<<NCH, 512, 0, stream>>>(counts, chunk_sums, row_ptr, cursor);
    scatter_kernel<<<1024, 256, 0, stream>>>(a, e, cursor, sorted_e, sorted_src);

    // rf = r @ Wa
    mfma_gemm<0, 0><<<(NA + 63) / 64, 256, 0, stream>>>(r, Wa, nullptr, buf0, NA);

    // fused edge pipeline, no global atomics
    edge_csr<<<NA / DPB, 256, 0, stream>>>(sorted_e, sorted_src, row_ptr,
                                           Wf2, bf2, buf0, seg);

    // y1 = ssp(seg @ W1 + b1); out = y1 @ W2 + b2
    mfma_gemm<1, 1><<<(NA + 63) / 64, 256, 0, stream>>>(seg, W1, b1, buf0, NA);
    mfma_gemm<0, 1><<<(NA + 63) / 64, 256, 0, stream>>>(buf0, W2, b2, out, NA);
}

// Round 4
// 521.715 us; speedup vs baseline: 1.5525x; 1.5525x over previous
//
#include <hip/hip_runtime.h>
#include <hip/hip_bf16.h>
#include <math.h>

#define NA 50000
#define NE 800000
#define NG 64

#define NBIN 50176            // NA rounded up to 98*512, zero-padded
#define NCH 98                // scan chunks of 512
#define DPW 16                // dsts per wave in edge_seg

typedef float f32x4 __attribute__((ext_vector_type(4)));
typedef __bf16 bf16x8 __attribute__((ext_vector_type(8)));

__device__ __forceinline__ float ssp(float x) {
    float sp = (x > 15.0f) ? x : log1pf(__expf(x));
    return sp - 0.69314718f;
}

// ---------------------------------------------------------------------------
// CSR build: histogram -> 3-phase exclusive scan -> scatter permutation
// ---------------------------------------------------------------------------
__global__ __launch_bounds__(256) void hist_kernel(const int* __restrict__ a,
                                                   int* __restrict__ counts) {
    for (int i = blockIdx.x * 256 + threadIdx.x; i < NE; i += gridDim.x * 256) {
        int2 dp = ((const int2*)a)[i];
        atomicAdd(&counts[dp.x], 1);
    }
}

__global__ __launch_bounds__(512) void scanA(const int* __restrict__ counts,
                                             int* __restrict__ chunk_sums) {
    __shared__ int red[512];
    int t = threadIdx.x;
    red[t] = counts[blockIdx.x * 512 + t];
    __syncthreads();
    for (int off = 256; off > 0; off >>= 1) {
        if (t < off) red[t] += red[t + off];
        __syncthreads();
    }
    if (t == 0) chunk_sums[blockIdx.x] = red[0];
}

__global__ __launch_bounds__(128) void scanB(int* __restrict__ chunk_sums) {
    __shared__ int s[128];
    int t = threadIdx.x;
    int v = (t < NCH) ? chunk_sums[t] : 0;
    s[t] = v;
    __syncthreads();
    for (int off = 1; off < 128; off <<= 1) {
        int add = (t >= off) ? s[t - off] : 0;
        __syncthreads();
        s[t] += add;
        __syncthreads();
    }
    if (t < NCH) chunk_sums[t] = s[t] - v;   // exclusive
}

__global__ __launch_bounds__(512) void scanC(const int* __restrict__ counts,
                                             const int* __restrict__ chunk_sums,
                                             int* __restrict__ row_ptr,
                                             int* __restrict__ cursor) {
    __shared__ int s[512];
    int t = threadIdx.x;
    int i = blockIdx.x * 512 + t;
    int v = counts[i];
    s[t] = v;
    __syncthreads();
    for (int off = 1; off < 512; off <<= 1) {
        int add = (t >= off) ? s[t - off] : 0;
        __syncthreads();
        s[t] += add;
        __syncthreads();
    }
    int excl = s[t] - v + chunk_sums[blockIdx.x];
    row_ptr[i] = excl;
    cursor[i]  = excl;
}

__global__ __launch_bounds__(256) void scatter_kernel(const int* __restrict__ a,
                                                      const float* __restrict__ e,
                                                      int* __restrict__ cursor,
                                                      float* __restrict__ sorted_e,
                                                      int* __restrict__ sorted_src) {
    for (int i = blockIdx.x * 256 + threadIdx.x; i < NE; i += gridDim.x * 256) {
        int2 dp = ((const int2*)a)[i];
        int pos = atomicAdd(&cursor[dp.x], 1);
        sorted_e[pos]   = e[i];
        sorted_src[pos] = dp.y;
    }
}

// ---------------------------------------------------------------------------
// Fused edge pipeline, no atomics, no main-loop barriers.
// One wave owns DPW dsts. Per dst: walk its sorted edges in 16-edge tiles
// (last tile padded). Per tile: gaussian A-frags -> MFMA filter (hi/lo bf16)
// -> gather rf[src] -> modulate -> accumulate in registers (per-lane over the
// 4 C-regs). Per dst: shfl-xor reduce over lane groups -> one plain store.
// ---------------------------------------------------------------------------
__global__ __launch_bounds__(256) void edge_seg(const float* __restrict__ sorted_e,
                                                const int* __restrict__ sorted_src,
                                                const int* __restrict__ row_ptr,
                                                const float* __restrict__ Wf2,
                                                const float* __restrict__ bf2,
                                                const float* __restrict__ rf,
                                                float* __restrict__ seg) {
    __shared__ __bf16 sWhi[128 * 64];   // Wf2^T hi, [n][k], k8 XOR swizzle
    __shared__ __bf16 sWlo[128 * 64];

    const int tid = threadIdx.x;
    for (int i = tid; i < 64 * 128; i += 256) {
        int k = i >> 7, n = i & 127;
        float v = Wf2[i];
        __bf16 h = (__bf16)v;
        __bf16 l = (__bf16)(v - (float)h);
        int addr = n * 64 + (((k >> 3) ^ (n & 7)) << 3) + (k & 7);
        sWhi[addr] = h;
        sWlo[addr] = l;
    }
    __syncthreads();

    const int lane = tid & 63, w = tid >> 6;
    const int lrow = lane & 15, lgrp = lane >> 4;
    const float coeff = -0.5f * (63.0f / 5.0f) * (63.0f / 5.0f);

    float bv[8];
    #pragma unroll
    for (int nt = 0; nt < 8; ++nt) bv[nt] = bf2[nt * 16 + lrow];

    const int d0 = (blockIdx.x * 4 + w) * DPW;

    for (int di = 0; di < DPW; ++di) {
        const int d = d0 + di;
        if (d >= NA) break;
        const int rp0  = row_ptr[d];
        const int rend = row_ptr[d + 1];

        float accs[8];
        #pragma unroll
        for (int nt = 0; nt < 8; ++nt) accs[nt] = 0.0f;

        for (int p = rp0; p < rend; p += 16) {
            // A fragments: this lane supplies row lrow of the 16x32 A tiles
            int pe = p + lrow;
            float ev = (pe < rend) ? sorted_e[pe] : 1.0e9f;   // pad -> g = 0
            bf16x8 ah[2], al[2];
            #pragma unroll
            for (int ks = 0; ks < 2; ++ks) {
                #pragma unroll
                for (int j = 0; j < 8; ++j) {
                    int k = ks * 32 + lgrp * 8 + j;
                    float dd = ev - (5.0f / 63.0f) * (float)k;
                    float g = __expf(coeff * dd * dd);
                    __bf16 h = (__bf16)g;
                    ah[ks][j] = h;
                    al[ks][j] = (__bf16)(g - (float)h);
                }
            }

            f32x4 c[8];
            #pragma unroll
            for (int nt = 0; nt < 8; ++nt) c[nt] = (f32x4){0.f, 0.f, 0.f, 0.f};

            #pragma unroll
            for (int ks = 0; ks < 2; ++ks) {
                #pragma unroll
                for (int nt = 0; nt < 8; ++nt) {
                    int n = nt * 16 + lrow;
                    int k8 = ks * 4 + lgrp;
                    int addr = n * 64 + ((k8 ^ (n & 7)) << 3);
                    bf16x8 bh = *(const bf16x8*)&sWhi[addr];
                    bf16x8 bl = *(const bf16x8*)&sWlo[addr];
                    c[nt] = __builtin_amdgcn_mfma_f32_16x16x32_bf16(ah[ks], bh, c[nt], 0, 0, 0);
                    c[nt] = __builtin_amdgcn_mfma_f32_16x16x32_bf16(ah[ks], bl, c[nt], 0, 0, 0);
                    c[nt] = __builtin_amdgcn_mfma_f32_16x16x32_bf16(al[ks], bh, c[nt], 0, 0, 0);
                }
            }

            // modulate + in-lane accumulate (C row m = lgrp*4 + r)
            #pragma unroll
            for (int r = 0; r < 4; ++r) {
                int p2 = p + lgrp * 4 + r;
                if (p2 < rend) {
                    int src = sorted_src[p2];
                    const float* rfp = rf + (size_t)src * 128 + lrow;
                    #pragma unroll
                    for (int nt = 0; nt < 8; ++nt)
                        accs[nt] = fmaf(rfp[nt * 16], c[nt][r] + bv[nt], accs[nt]);
                }
            }
        }

        // cross-lane reduce over the 4 lane-groups, then store the dst row
        #pragma unroll
        for (int nt = 0; nt < 8; ++nt) {
            accs[nt] += __shfl_xor(accs[nt], 16);
            accs[nt] += __shfl_xor(accs[nt], 32);
        }
        if (lgrp == 0) {
            float* op = seg + (size_t)d * 128 + lrow;
            #pragma unroll
            for (int nt = 0; nt < 8; ++nt) op[nt * 16] = accs[nt];
        }
    }
}

// ---------------------------------------------------------------------------
// Dense GEMM: C[M,128] = act(A[M,128] @ W[128,128] + b), hi/lo split MFMA.
// Grid-stride over 64-row chunks to amortize the weight-staging prologue.
// ---------------------------------------------------------------------------
template<int ACT, int BIAS>
__global__ __launch_bounds__(256) void mfma_gemm(const float* __restrict__ A,
                                                 const float* __restrict__ W,
                                                 const float* __restrict__ b,
                                                 float* __restrict__ C, int M) {
    __shared__ __bf16 sWhi[128 * 128];
    __shared__ __bf16 sWlo[128 * 128];

    const int tid = threadIdx.x;
    for (int i = tid; i < 128 * 128; i += 256) {
        int k = i >> 7, n = i & 127;
        float v = W[i];
        __bf16 h = (__bf16)v;
        __bf16 l = (__bf16)(v - (float)h);
        int addr = n * 128 + (((k >> 3) ^ (n & 15)) << 3) + (k & 7);
        sWhi[addr] = h;
        sWlo[addr] = l;
    }
    __syncthreads();

    const int lane = tid & 63, w = tid >> 6;
    const int lrow = lane & 15, lgrp = lane >> 4;

    float bv[8];
    #pragma unroll
    for (int nt = 0; nt < 8; ++nt) bv[nt] = BIAS ? b[nt * 16 + lrow] : 0.0f;

    for (int base = blockIdx.x * 64; base < M; base += gridDim.x * 64) {
        const int row  = base + w * 16 + lrow;
        const int rowc = row < M ? row : M - 1;

        f32x4 acc[8];
        #pragma unroll
        for (int nt = 0; nt < 8; ++nt) acc[nt] = (f32x4){0.f, 0.f, 0.f, 0.f};

        #pragma unroll
        for (int ks = 0; ks < 4; ++ks) {
            int k0 = ks * 32 + lgrp * 8;
            float4 f0 = *(const float4*)&A[(size_t)rowc * 128 + k0];
            float4 f1 = *(const float4*)&A[(size_t)rowc * 128 + k0 + 4];
            float av[8] = {f0.x, f0.y, f0.z, f0.w, f1.x, f1.y, f1.z, f1.w};
            bf16x8 ah, al;
            #pragma unroll
            for (int j = 0; j < 8; ++j) {
                __bf16 h = (__bf16)av[j];
                ah[j] = h;
                al[j] = (__bf16)(av[j] - (float)h);
            }
            #pragma unroll
            for (int nt = 0; nt < 8; ++nt) {
                int n = nt * 16 + lrow;
                int k8 = ks * 4 + lgrp;
                int addr = n * 128 + ((k8 ^ (n & 15)) << 3);
                bf16x8 bh = *(const bf16x8*)&sWhi[addr];
                bf16x8 bl = *(const bf16x8*)&sWlo[addr];
                acc[nt] = __builtin_amdgcn_mfma_f32_16x16x32_bf16(ah, bh, acc[nt], 0, 0, 0);
                acc[nt] = __builtin_amdgcn_mfma_f32_16x16x32_bf16(ah, bl, acc[nt], 0, 0, 0);
                acc[nt] = __builtin_amdgcn_mfma_f32_16x16x32_bf16(al, bh, acc[nt], 0, 0, 0);
            }
        }

        const int orow = base + w * 16 + lgrp * 4;
        #pragma unroll
        for (int r = 0; r < 4; ++r) {
            if (orow + r < M) {
                #pragma unroll
                for (int nt = 0; nt < 8; ++nt) {
                    float v = acc[nt][r] + bv[nt];
                    if (ACT) v = ssp(v);
                    C[(size_t)(orow + r) * 128 + nt * 16 + lrow] = v;
                }
            }
        }
    }
}

extern "C" void kernel_launch(void* const* d_in, const int* in_sizes, int n_in,
                              void* d_out, int out_size, void* d_ws, size_t ws_size,
                              hipStream_t stream) {
    const float* r   = (const float*)d_in[0];
    const float* e   = (const float*)d_in[1];
    const float* Wf2 = (const float*)d_in[2];
    const float* bf2 = (const float*)d_in[3];
    const float* Wa  = (const float*)d_in[4];
    const float* W1  = (const float*)d_in[5];
    const float* b1  = (const float*)d_in[6];
    const float* W2  = (const float*)d_in[7];
    const float* b2  = (const float*)d_in[8];
    const int*   a   = (const int*)d_in[9];

    float* out = (float*)d_out;

    // workspace layout (4B words)
    float* buf0       = (float*)d_ws;                 // rf / y1   (6.4M words)
    int*   counts     = (int*)d_ws + 6400000;         // NBIN
    int*   row_ptr    = counts + NBIN;                // NBIN
    int*   cursor     = row_ptr + NBIN;               // NBIN
    int*   chunk_sums = cursor + NBIN;                // 128
    float* sorted_e   = (float*)(chunk_sums + 128);   // NE
    int*   sorted_src = (int*)(sorted_e + NE);        // NE

    float* seg = out;   // d_out doubles as segment-sum buffer

    // --- CSR build ---
    hipMemsetAsync(counts, 0, NBIN * sizeof(int), stream);
    hist_kernel<<<1024, 256, 0, stream>>>(a, counts);
    scanA<<<NCH, 512, 0, stream>>>(counts, chunk_sums);
    scanB<<<1, 128, 0, stream>>>(chunk_sums);
    scanC<<<NCH, 512, 0, stream>>>(counts, chunk_sums, row_ptr, cursor);
    scatter_kernel<<<1024, 256, 0, stream>>>(a, e, cursor, sorted_e, sorted_src);

    // rf = r @ Wa
    mfma_gemm<0, 0><<<512, 256, 0, stream>>>(r, Wa, nullptr, buf0, NA);

    // fused edge pipeline: wave-exclusive dst ownership, register reduction
    edge_seg<<<(NA + 4 * DPW - 1) / (4 * DPW), 256, 0, stream>>>(
        sorted_e, sorted_src, row_ptr, Wf2, bf2, buf0, seg);

    // y1 = ssp(seg @ W1 + b1); out = y1 @ W2 + b2
    mfma_gemm<1, 1><<<512, 256, 0, stream>>>(seg, W1, b1, buf0, NA);
    mfma_gemm<0, 1><<<512, 256, 0, stream>>>(buf0, W2, b2, out, NA);
}

// Round 5
// 373.161 us; speedup vs baseline: 2.1705x; 1.3981x over previous
//
#include <hip/hip_runtime.h>
#include <hip/hip_bf16.h>
#include <math.h>

#define NA 50000
#define NE 800000
#define NBIN 50176            // NA rounded to 98*512
#define NCH 98
#define DPW 16                // dsts per wave
#define WPB 4                 // waves per block

typedef float f32x4 __attribute__((ext_vector_type(4)));
typedef __bf16 bf16x8 __attribute__((ext_vector_type(8)));

__device__ __forceinline__ float ssp(float x) {
    float sp = (x > 15.0f) ? x : log1pf(__expf(x));
    return sp - 0.69314718f;
}

// ---------------------------------------------------------------------------
// CSR build
// ---------------------------------------------------------------------------
__global__ __launch_bounds__(256) void hist_kernel(const int* __restrict__ a,
                                                   int* __restrict__ counts) {
    for (int i = blockIdx.x * 256 + threadIdx.x; i < NE; i += gridDim.x * 256) {
        int2 dp = ((const int2*)a)[i];
        atomicAdd(&counts[dp.x], 1);
    }
}

__global__ __launch_bounds__(512) void scanA(const int* __restrict__ counts,
                                             int* __restrict__ chunk_sums) {
    __shared__ int red[512];
    int t = threadIdx.x;
    red[t] = counts[blockIdx.x * 512 + t];
    __syncthreads();
    for (int off = 256; off > 0; off >>= 1) {
        if (t < off) red[t] += red[t + off];
        __syncthreads();
    }
    if (t == 0) chunk_sums[blockIdx.x] = red[0];
}

__global__ __launch_bounds__(128) void scanB(int* __restrict__ chunk_sums) {
    __shared__ int s[128];
    int t = threadIdx.x;
    int v = (t < NCH) ? chunk_sums[t] : 0;
    s[t] = v;
    __syncthreads();
    for (int off = 1; off < 128; off <<= 1) {
        int add = (t >= off) ? s[t - off] : 0;
        __syncthreads();
        s[t] += add;
        __syncthreads();
    }
    if (t < NCH) chunk_sums[t] = s[t] - v;
}

__global__ __launch_bounds__(512) void scanC(const int* __restrict__ counts,
                                             const int* __restrict__ chunk_sums,
                                             int* __restrict__ row_ptr,
                                             int* __restrict__ cursor) {
    __shared__ int s[512];
    int t = threadIdx.x;
    int i = blockIdx.x * 512 + t;
    int v = counts[i];
    s[t] = v;
    __syncthreads();
    for (int off = 1; off < 512; off <<= 1) {
        int add = (t >= off) ? s[t - off] : 0;
        __syncthreads();
        s[t] += add;
        __syncthreads();
    }
    int excl = s[t] - v + chunk_sums[blockIdx.x];
    row_ptr[i] = excl;
    cursor[i]  = excl;
}

__global__ __launch_bounds__(256) void scatter_kernel(const int* __restrict__ a,
                                                      const float* __restrict__ e,
                                                      int* __restrict__ cursor,
                                                      float2* __restrict__ ses) {
    for (int i = blockIdx.x * 256 + threadIdx.x; i < NE; i += gridDim.x * 256) {
        int2 dp = ((const int2*)a)[i];
        int pos = atomicAdd(&cursor[dp.x], 1);
        float2 v; v.x = e[i]; v.y = __int_as_float(dp.y);
        ses[pos] = v;   // single packed 8B store
    }
}

// ---------------------------------------------------------------------------
// Fused edge pipeline: dense 32-edge chunks crossing dst boundaries.
// Wave owns DPW dsts. Per chunk: gaussians -> MFMA filter -> bf16 bounce tile
// in wave-private LDS -> per-edge coalesced rf-row gather + fma into 2 regs
// (lane owns f=2l,2l+1) with uniform two-pointer dst-boundary flush.
// No atomics, no block barriers in the main loop.
// ---------------------------------------------------------------------------
__global__ __launch_bounds__(256) void edge_fused(const float2* __restrict__ ses,
                                                  const int* __restrict__ row_ptr,
                                                  const float* __restrict__ Wf2,
                                                  const float* __restrict__ bf2,
                                                  const float* __restrict__ rf,
                                                  float* __restrict__ seg) {
    __shared__ __bf16 sWf[128 * 64];      // Wf2^T bf16, [n][k], k8 XOR swizzle
    __shared__ __bf16 sP[WPB][32 * 128];  // per-wave bounce [e][f], 16B-gran XOR
    __shared__ float  sse[WPB][32];
    __shared__ int    sssrc[WPB][32];
    __shared__ int    ssrp[WPB][DPW + 2];

    const int tid  = threadIdx.x;
    const int lane = tid & 63, w = tid >> 6;
    const int lrow = lane & 15, lgrp = lane >> 4;

    {
        const float4* W4 = (const float4*)Wf2;
        for (int i = tid; i < 64 * 128 / 4; i += 256) {
            float4 v = W4[i];
            #pragma unroll
            for (int q = 0; q < 4; ++q) {
                int idx = i * 4 + q;
                int k = idx >> 7, n = idx & 127;
                float x = ((const float*)&v)[q];
                int addr = n * 64 + (((k >> 3) ^ (n & 7)) << 3) + (k & 7);
                sWf[addr] = (__bf16)x;
            }
        }
    }
    const int d0 = (blockIdx.x * WPB + w) * DPW;
    if (lane <= DPW)     ssrp[w][lane] = row_ptr[d0 + lane];  // d0+DPW <= 50048 < NBIN
    if (lane == DPW + 1) ssrp[w][lane] = 0x7FFFFFFF;
    __syncthreads();

    float bv[8];
    #pragma unroll
    for (int nt = 0; nt < 8; ++nt) bv[nt] = bf2[nt * 16 + lrow];

    const float coeff = -0.5f * (63.0f / 5.0f) * (63.0f / 5.0f);
    float* sse_w = sse[w];
    int*   ssrc_w = sssrc[w];
    int*   srp_w = ssrp[w];
    __bf16* myP = sP[w];
    const uint32_t* myPu = (const uint32_t*)myP;

    const int rp0 = srp_w[0], rend = srp_w[DPW];
    int ld = 0;
    int nextb = srp_w[1];
    float racc0 = 0.0f, racc1 = 0.0f;

    for (int p = rp0; p < rend; p += 32) {
        const int cnt = (rend - p < 32) ? (rend - p) : 32;
        if (lane < 32) {
            float2 v;
            if (lane < cnt) v = ses[p + lane];
            else { v.x = 0.0f; v.y = 0.0f; }
            sse_w[lane]  = v.x;
            ssrc_w[lane] = __float_as_int(v.y);
        }
        __builtin_amdgcn_wave_barrier();

        // gaussian A fragments (hi/lo split of g)
        bf16x8 ah[2][2], al[2][2];
        #pragma unroll
        for (int mt = 0; mt < 2; ++mt) {
            float ev = sse_w[mt * 16 + lrow];
            #pragma unroll
            for (int ks = 0; ks < 2; ++ks) {
                #pragma unroll
                for (int j = 0; j < 8; ++j) {
                    int k = ks * 32 + lgrp * 8 + j;
                    float dd = ev - (5.0f / 63.0f) * (float)k;
                    float g = __expf(coeff * dd * dd);
                    __bf16 h = (__bf16)g;
                    ah[mt][ks][j] = h;
                    al[mt][ks][j] = (__bf16)(g - (float)h);
                }
            }
        }

        // filter MFMA + bias + bf16 bounce, two f-halves to cap VGPRs
        #pragma unroll
        for (int nh = 0; nh < 2; ++nh) {
            f32x4 c[2][4];
            #pragma unroll
            for (int mt = 0; mt < 2; ++mt)
                #pragma unroll
                for (int nt = 0; nt < 4; ++nt)
                    c[mt][nt] = (f32x4){0.f, 0.f, 0.f, 0.f};
            #pragma unroll
            for (int ks = 0; ks < 2; ++ks) {
                #pragma unroll
                for (int nt = 0; nt < 4; ++nt) {
                    int n = (nh * 4 + nt) * 16 + lrow;
                    int addr = n * 64 + (((ks * 4 + lgrp) ^ (n & 7)) << 3);
                    bf16x8 bh = *(const bf16x8*)&sWf[addr];
                    c[0][nt] = __builtin_amdgcn_mfma_f32_16x16x32_bf16(ah[0][ks], bh, c[0][nt], 0, 0, 0);
                    c[0][nt] = __builtin_amdgcn_mfma_f32_16x16x32_bf16(al[0][ks], bh, c[0][nt], 0, 0, 0);
                    c[1][nt] = __builtin_amdgcn_mfma_f32_16x16x32_bf16(ah[1][ks], bh, c[1][nt], 0, 0, 0);
                    c[1][nt] = __builtin_amdgcn_mfma_f32_16x16x32_bf16(al[1][ks], bh, c[1][nt], 0, 0, 0);
                }
            }
            #pragma unroll
            for (int mt = 0; mt < 2; ++mt)
                #pragma unroll
                for (int nt = 0; nt < 4; ++nt) {
                    int f = (nh * 4 + nt) * 16 + lrow;
                    #pragma unroll
                    for (int r = 0; r < 4; ++r) {
                        int e2 = mt * 16 + lgrp * 4 + r;
                        float v = c[mt][nt][r] + bv[nh * 4 + nt];
                        myP[e2 * 128 + (((f >> 3) ^ (e2 & 7)) << 3) + (f & 7)] = (__bf16)v;
                    }
                }
        }
        __builtin_amdgcn_wave_barrier();

        // per-edge: coalesced rf row + bounce read + boundary walk
        #pragma unroll 8
        for (int j = 0; j < cnt; ++j) {
            int src = ssrc_w[j];
            float2 rv = *(const float2*)&rf[(size_t)src * 128 + lane * 2];
            uint32_t u = myPu[j * 64 + (((lane >> 2) ^ (j & 7)) << 2) + (lane & 3)];
            while (p + j >= nextb) {               // wave-uniform
                if (d0 + ld < NA) {
                    float2 st; st.x = racc0; st.y = racc1;
                    *(float2*)&seg[(size_t)(d0 + ld) * 128 + lane * 2] = st;
                }
                racc0 = 0.0f; racc1 = 0.0f;
                ++ld;
                nextb = srp_w[ld + 1];
            }
            racc0 = fmaf(rv.x, __uint_as_float(u << 16), racc0);
            racc1 = fmaf(rv.y, __uint_as_float(u & 0xFFFF0000u), racc1);
        }
    }
    // flush remaining dsts (incl. empty ones)
    while (ld < DPW) {
        if (d0 + ld < NA) {
            float2 st; st.x = racc0; st.y = racc1;
            *(float2*)&seg[(size_t)(d0 + ld) * 128 + lane * 2] = st;
        }
        racc0 = 0.0f; racc1 = 0.0f;
        ++ld;
    }
}

// ---------------------------------------------------------------------------
// Dense GEMM: C[M,128] = act(A[M,128] @ W[128,128] + b), 3-term hi/lo MFMA.
// ---------------------------------------------------------------------------
template<int ACT, int BIAS>
__global__ __launch_bounds__(256) void mfma_gemm(const float* __restrict__ A,
                                                 const float* __restrict__ W,
                                                 const float* __restrict__ b,
                                                 float* __restrict__ C, int M) {
    __shared__ __bf16 sWhi[128 * 128];
    __shared__ __bf16 sWlo[128 * 128];

    const int tid = threadIdx.x;
    {
        const float4* W4 = (const float4*)W;
        for (int i = tid; i < 128 * 128 / 4; i += 256) {
            float4 v = W4[i];
            #pragma unroll
            for (int q = 0; q < 4; ++q) {
                int idx = i * 4 + q;
                int k = idx >> 7, n = idx & 127;
                float x = ((const float*)&v)[q];
                __bf16 h = (__bf16)x;
                __bf16 l = (__bf16)(x - (float)h);
                int addr = n * 128 + (((k >> 3) ^ (n & 15)) << 3) + (k & 7);
                sWhi[addr] = h;
                sWlo[addr] = l;
            }
        }
    }
    __syncthreads();

    const int lane = tid & 63, w = tid >> 6;
    const int lrow = lane & 15, lgrp = lane >> 4;

    float bv[8];
    #pragma unroll
    for (int nt = 0; nt < 8; ++nt) bv[nt] = BIAS ? b[nt * 16 + lrow] : 0.0f;

    for (int base = blockIdx.x * 64; base < M; base += gridDim.x * 64) {
        const int row  = base + w * 16 + lrow;
        const int rowc = row < M ? row : M - 1;

        f32x4 acc[8];
        #pragma unroll
        for (int nt = 0; nt < 8; ++nt) acc[nt] = (f32x4){0.f, 0.f, 0.f, 0.f};

        #pragma unroll
        for (int ks = 0; ks < 4; ++ks) {
            int k0 = ks * 32 + lgrp * 8;
            float4 f0 = *(const float4*)&A[(size_t)rowc * 128 + k0];
            float4 f1 = *(const float4*)&A[(size_t)rowc * 128 + k0 + 4];
            float av[8] = {f0.x, f0.y, f0.z, f0.w, f1.x, f1.y, f1.z, f1.w};
            bf16x8 ah, al;
            #pragma unroll
            for (int j = 0; j < 8; ++j) {
                __bf16 h = (__bf16)av[j];
                ah[j] = h;
                al[j] = (__bf16)(av[j] - (float)h);
            }
            #pragma unroll
            for (int nt = 0; nt < 8; ++nt) {
                int n = nt * 16 + lrow;
                int k8 = ks * 4 + lgrp;
                int addr = n * 128 + ((k8 ^ (n & 15)) << 3);
                bf16x8 bh = *(const bf16x8*)&sWhi[addr];
                bf16x8 bl = *(const bf16x8*)&sWlo[addr];
                acc[nt] = __builtin_amdgcn_mfma_f32_16x16x32_bf16(ah, bh, acc[nt], 0, 0, 0);
                acc[nt] = __builtin_amdgcn_mfma_f32_16x16x32_bf16(ah, bl, acc[nt], 0, 0, 0);
                acc[nt] = __builtin_amdgcn_mfma_f32_16x16x32_bf16(al, bh, acc[nt], 0, 0, 0);
            }
        }

        const int orow = base + w * 16 + lgrp * 4;
        #pragma unroll
        for (int r = 0; r < 4; ++r) {
            if (orow + r < M) {
                #pragma unroll
                for (int nt = 0; nt < 8; ++nt) {
                    float v = acc[nt][r] + bv[nt];
                    if (ACT) v = ssp(v);
                    C[(size_t)(orow + r) * 128 + nt * 16 + lrow] = v;
                }
            }
        }
    }
}

extern "C" void kernel_launch(void* const* d_in, const int* in_sizes, int n_in,
                              void* d_out, int out_size, void* d_ws, size_t ws_size,
                              hipStream_t stream) {
    const float* r   = (const float*)d_in[0];
    const float* e   = (const float*)d_in[1];
    const float* Wf2 = (const float*)d_in[2];
    const float* bf2 = (const float*)d_in[3];
    const float* Wa  = (const float*)d_in[4];
    const float* W1  = (const float*)d_in[5];
    const float* b1  = (const float*)d_in[6];
    const float* W2  = (const float*)d_in[7];
    const float* b2  = (const float*)d_in[8];
    const int*   a   = (const int*)d_in[9];

    float* out = (float*)d_out;

    // workspace layout (4B words)
    float*  buf0       = (float*)d_ws;                 // rf / y1 (6.4M words)
    int*    counts     = (int*)d_ws + 6400000;         // NBIN
    int*    row_ptr    = counts + NBIN;                // NBIN
    int*    cursor     = row_ptr + NBIN;               // NBIN
    int*    chunk_sums = cursor + NBIN;                // 128
    float2* ses        = (float2*)(chunk_sums + 128);  // NE packed (e, src)

    float* seg = out;   // d_out doubles as segment-sum buffer (fully overwritten)

    // CSR build
    hipMemsetAsync(counts, 0, NBIN * sizeof(int), stream);
    hist_kernel<<<1024, 256, 0, stream>>>(a, counts);
    scanA<<<NCH, 512, 0, stream>>>(counts, chunk_sums);
    scanB<<<1, 128, 0, stream>>>(chunk_sums);
    scanC<<<NCH, 512, 0, stream>>>(counts, chunk_sums, row_ptr, cursor);
    scatter_kernel<<<1024, 256, 0, stream>>>(a, e, cursor, ses);

    // rf = r @ Wa
    mfma_gemm<0, 0><<<391, 256, 0, stream>>>(r, Wa, nullptr, buf0, NA);

    // fused edge pipeline
    edge_fused<<<(NA + WPB * DPW - 1) / (WPB * DPW), 256, 0, stream>>>(
        ses, row_ptr, Wf2, bf2, buf0, seg);

    // y1 = ssp(seg @ W1 + b1); out = y1 @ W2 + b2
    mfma_gemm<1, 1><<<391, 256, 0, stream>>>(seg, W1, b1, buf0, NA);
    mfma_gemm<0, 1><<<391, 256, 0, stream>>>(buf0, W2, b2, out, NA);
}

// Round 6
// 351.867 us; speedup vs baseline: 2.3018x; 1.0605x over previous
//
#include <hip/hip_runtime.h>
#include <hip/hip_bf16.h>
#include <math.h>

#define NA 50000
#define NE 800000
#define NBIN 50176            // NA rounded to 98*512
#define NCH 98
#define WPB 4                 // waves per block
#define EGRID 768             // edge_fused blocks (exactly 3/CU)
#define NWAVES (EGRID * WPB)  // 3072

typedef float f32x4 __attribute__((ext_vector_type(4)));
typedef __bf16 bf16x8 __attribute__((ext_vector_type(8)));

__device__ __forceinline__ float ssp(float x) {
    float sp = (x > 15.0f) ? x : log1pf(__expf(x));
    return sp - 0.69314718f;
}

// ---------------------------------------------------------------------------
// CSR build
// ---------------------------------------------------------------------------
__global__ __launch_bounds__(256) void hist_kernel(const int* __restrict__ a,
                                                   int* __restrict__ counts) {
    for (int i = blockIdx.x * 256 + threadIdx.x; i < NE; i += gridDim.x * 256) {
        int2 dp = ((const int2*)a)[i];
        atomicAdd(&counts[dp.x], 1);
    }
}

__global__ __launch_bounds__(512) void scanA(const int* __restrict__ counts,
                                             int* __restrict__ chunk_sums) {
    __shared__ int red[512];
    int t = threadIdx.x;
    red[t] = counts[blockIdx.x * 512 + t];
    __syncthreads();
    for (int off = 256; off > 0; off >>= 1) {
        if (t < off) red[t] += red[t + off];
        __syncthreads();
    }
    if (t == 0) chunk_sums[blockIdx.x] = red[0];
}

__global__ __launch_bounds__(128) void scanB(int* __restrict__ chunk_sums) {
    __shared__ int s[128];
    int t = threadIdx.x;
    int v = (t < NCH) ? chunk_sums[t] : 0;
    s[t] = v;
    __syncthreads();
    for (int off = 1; off < 128; off <<= 1) {
        int add = (t >= off) ? s[t - off] : 0;
        __syncthreads();
        s[t] += add;
        __syncthreads();
    }
    if (t < NCH) chunk_sums[t] = s[t] - v;
}

__global__ __launch_bounds__(512) void scanC(const int* __restrict__ counts,
                                             const int* __restrict__ chunk_sums,
                                             int* __restrict__ row_ptr,
                                             int* __restrict__ cursor) {
    __shared__ int s[512];
    int t = threadIdx.x;
    int i = blockIdx.x * 512 + t;
    int v = counts[i];
    s[t] = v;
    __syncthreads();
    for (int off = 1; off < 512; off <<= 1) {
        int add = (t >= off) ? s[t - off] : 0;
        __syncthreads();
        s[t] += add;
        __syncthreads();
    }
    int excl = s[t] - v + chunk_sums[blockIdx.x];
    row_ptr[i] = excl;
    cursor[i]  = excl;
}

__global__ __launch_bounds__(256) void scatter_kernel(const int* __restrict__ a,
                                                      const float* __restrict__ e,
                                                      int* __restrict__ cursor,
                                                      float2* __restrict__ ses) {
    for (int i = blockIdx.x * 256 + threadIdx.x; i < NE; i += gridDim.x * 256) {
        int2 dp = ((const int2*)a)[i];
        int pos = atomicAdd(&cursor[dp.x], 1);
        float2 v; v.x = e[i]; v.y = __int_as_float(dp.y);
        ses[pos] = v;
    }
}

// ---------------------------------------------------------------------------
// Fused edge pipeline: dense 32-edge chunks crossing dst boundaries.
// Wave wi owns dsts [wi*NA/NWAVES, (wi+1)*NA/NWAVES) (16-17 dsts, balanced).
// Per chunk: gaussians -> MFMA filter -> bf16 bounce tile (wave-private LDS)
// -> batched 8-deep gather phase (pure loads) -> consume phase (fma +
// uniform two-pointer boundary flush). No atomics, no block barriers.
// ---------------------------------------------------------------------------
__global__ __launch_bounds__(256) void edge_fused(const float2* __restrict__ ses,
                                                  const int* __restrict__ row_ptr,
                                                  const float* __restrict__ Wf2,
                                                  const float* __restrict__ bf2,
                                                  const float* __restrict__ rf,
                                                  float* __restrict__ seg) {
    __shared__ __bf16 sWf[128 * 64];      // Wf2^T bf16, [n][k], k8 XOR swizzle
    __shared__ __bf16 sP[WPB][32 * 128];  // per-wave bounce [e][f], 16B-gran XOR
    __shared__ float  sse[WPB][32];
    __shared__ int    sssrc[WPB][32];
    __shared__ int    ssrp[WPB][20];

    const int tid  = threadIdx.x;
    const int lane = tid & 63, w = tid >> 6;
    const int lrow = lane & 15, lgrp = lane >> 4;

    {
        const float4* W4 = (const float4*)Wf2;
        for (int i = tid; i < 64 * 128 / 4; i += 256) {
            float4 v = W4[i];
            #pragma unroll
            for (int q = 0; q < 4; ++q) {
                int idx = i * 4 + q;
                int k = idx >> 7, n = idx & 127;
                float x = ((const float*)&v)[q];
                int addr = n * 64 + (((k >> 3) ^ (n & 7)) << 3) + (k & 7);
                sWf[addr] = (__bf16)x;
            }
        }
    }
    const int wi      = blockIdx.x * WPB + w;
    const int d_start = (int)(((long long)wi * NA) / NWAVES);
    const int d_end   = (int)(((long long)(wi + 1) * NA) / NWAVES);
    const int dcount  = d_end - d_start;            // 16 or 17
    if (lane <= dcount)     ssrp[w][lane] = row_ptr[d_start + lane];
    if (lane == dcount + 1) ssrp[w][lane] = 0x7FFFFFFF;
    __syncthreads();

    float bv[8];
    #pragma unroll
    for (int nt = 0; nt < 8; ++nt) bv[nt] = bf2[nt * 16 + lrow];

    const float coeff = -0.5f * (63.0f / 5.0f) * (63.0f / 5.0f);
    float* sse_w  = sse[w];
    int*   ssrc_w = sssrc[w];
    int*   srp_w  = ssrp[w];
    __bf16* myP   = sP[w];
    const uint32_t* myPu = (const uint32_t*)myP;

    const int rp0 = srp_w[0], rend = srp_w[dcount];
    int ld = 0;
    int nextb = srp_w[1];
    float racc0 = 0.0f, racc1 = 0.0f;

    for (int p = rp0; p < rend; p += 32) {
        const int cnt = (rend - p < 32) ? (rend - p) : 32;
        if (lane < 32) {
            float2 v;
            if (lane < cnt) v = ses[p + lane];
            else { v.x = 0.0f; v.y = 0.0f; }
            sse_w[lane]  = v.x;
            ssrc_w[lane] = __float_as_int(v.y);
        }
        __builtin_amdgcn_wave_barrier();

        // gaussian A fragments (hi/lo split of g)
        bf16x8 ah[2][2], al[2][2];
        #pragma unroll
        for (int mt = 0; mt < 2; ++mt) {
            float ev = sse_w[mt * 16 + lrow];
            #pragma unroll
            for (int ks = 0; ks < 2; ++ks) {
                #pragma unroll
                for (int j = 0; j < 8; ++j) {
                    int k = ks * 32 + lgrp * 8 + j;
                    float dd = ev - (5.0f / 63.0f) * (float)k;
                    float g = __expf(coeff * dd * dd);
                    __bf16 h = (__bf16)g;
                    ah[mt][ks][j] = h;
                    al[mt][ks][j] = (__bf16)(g - (float)h);
                }
            }
        }

        // filter MFMA + bias + bf16 bounce, two f-halves to cap VGPRs
        #pragma unroll
        for (int nh = 0; nh < 2; ++nh) {
            f32x4 c[2][4];
            #pragma unroll
            for (int mt = 0; mt < 2; ++mt)
                #pragma unroll
                for (int nt = 0; nt < 4; ++nt)
                    c[mt][nt] = (f32x4){0.f, 0.f, 0.f, 0.f};
            #pragma unroll
            for (int ks = 0; ks < 2; ++ks) {
                #pragma unroll
                for (int nt = 0; nt < 4; ++nt) {
                    int n = (nh * 4 + nt) * 16 + lrow;
                    int addr = n * 64 + (((ks * 4 + lgrp) ^ (n & 7)) << 3);
                    bf16x8 bh = *(const bf16x8*)&sWf[addr];
                    c[0][nt] = __builtin_amdgcn_mfma_f32_16x16x32_bf16(ah[0][ks], bh, c[0][nt], 0, 0, 0);
                    c[0][nt] = __builtin_amdgcn_mfma_f32_16x16x32_bf16(al[0][ks], bh, c[0][nt], 0, 0, 0);
                    c[1][nt] = __builtin_amdgcn_mfma_f32_16x16x32_bf16(ah[1][ks], bh, c[1][nt], 0, 0, 0);
                    c[1][nt] = __builtin_amdgcn_mfma_f32_16x16x32_bf16(al[1][ks], bh, c[1][nt], 0, 0, 0);
                }
            }
            #pragma unroll
            for (int mt = 0; mt < 2; ++mt)
                #pragma unroll
                for (int nt = 0; nt < 4; ++nt) {
                    int f = (nh * 4 + nt) * 16 + lrow;
                    #pragma unroll
                    for (int r = 0; r < 4; ++r) {
                        int e2 = mt * 16 + lgrp * 4 + r;
                        float v = c[mt][nt][r] + bv[nh * 4 + nt];
                        myP[e2 * 128 + (((f >> 3) ^ (e2 & 7)) << 3) + (f & 7)] = (__bf16)v;
                    }
                }
        }
        __builtin_amdgcn_wave_barrier();

        // batched gather (pure load phase) + consume (fma + boundary walk)
        for (int j0 = 0; j0 < cnt; j0 += 8) {
            float2   rv[8];
            uint32_t uu[8];
            #pragma unroll
            for (int j = 0; j < 8; ++j) {
                int jj = j0 + j;
                int src = ssrc_w[jj];
                rv[j] = *(const float2*)&rf[(size_t)src * 128 + lane * 2];
                uu[j] = myPu[jj * 64 + (((lane >> 2) ^ (jj & 7)) << 2) + (lane & 3)];
            }
            #pragma unroll
            for (int j = 0; j < 8; ++j) {
                int gj = p + j0 + j;
                if (gj < rend) {                       // wave-uniform
                    while (gj >= nextb) {              // wave-uniform
                        float2 st; st.x = racc0; st.y = racc1;
                        *(float2*)&seg[(size_t)(d_start + ld) * 128 + lane * 2] = st;
                        racc0 = 0.0f; racc1 = 0.0f;
                        ++ld;
                        nextb = srp_w[ld + 1];
                    }
                    racc0 = fmaf(rv[j].x, __uint_as_float(uu[j] << 16), racc0);
                    racc1 = fmaf(rv[j].y, __uint_as_float(uu[j] & 0xFFFF0000u), racc1);
                }
            }
        }
    }
    // flush remaining dsts (incl. trailing empty ones)
    while (ld < dcount) {
        float2 st; st.x = racc0; st.y = racc1;
        *(float2*)&seg[(size_t)(d_start + ld) * 128 + lane * 2] = st;
        racc0 = 0.0f; racc1 = 0.0f;
        ++ld;
    }
}

// ---------------------------------------------------------------------------
// Dense GEMM: C[M,128] = act(A[M,128] @ W[128,128] + b), 3-term hi/lo MFMA.
// ---------------------------------------------------------------------------
template<int ACT, int BIAS>
__global__ __launch_bounds__(256) void mfma_gemm(const float* __restrict__ A,
                                                 const float* __restrict__ W,
                                                 const float* __restrict__ b,
                                                 float* __restrict__ C, int M) {
    __shared__ __bf16 sWhi[128 * 128];
    __shared__ __bf16 sWlo[128 * 128];

    const int tid = threadIdx.x;
    {
        const float4* W4 = (const float4*)W;
        for (int i = tid; i < 128 * 128 / 4; i += 256) {
            float4 v = W4[i];
            #pragma unroll
            for (int q = 0; q < 4; ++q) {
                int idx = i * 4 + q;
                int k = idx >> 7, n = idx & 127;
                float x = ((const float*)&v)[q];
                __bf16 h = (__bf16)x;
                __bf16 l = (__bf16)(x - (float)h);
                int addr = n * 128 + (((k >> 3) ^ (n & 15)) << 3) + (k & 7);
                sWhi[addr] = h;
                sWlo[addr] = l;
            }
        }
    }
    __syncthreads();

    const int lane = tid & 63, w = tid >> 6;
    const int lrow = lane & 15, lgrp = lane >> 4;

    float bv[8];
    #pragma unroll
    for (int nt = 0; nt < 8; ++nt) bv[nt] = BIAS ? b[nt * 16 + lrow] : 0.0f;

    for (int base = blockIdx.x * 64; base < M; base += gridDim.x * 64) {
        const int row  = base + w * 16 + lrow;
        const int rowc = row < M ? row : M - 1;

        f32x4 acc[8];
        #pragma unroll
        for (int nt = 0; nt < 8; ++nt) acc[nt] = (f32x4){0.f, 0.f, 0.f, 0.f};

        #pragma unroll
        for (int ks = 0; ks < 4; ++ks) {
            int k0 = ks * 32 + lgrp * 8;
            float4 f0 = *(const float4*)&A[(size_t)rowc * 128 + k0];
            float4 f1 = *(const float4*)&A[(size_t)rowc * 128 + k0 + 4];
            float av[8] = {f0.x, f0.y, f0.z, f0.w, f1.x, f1.y, f1.z, f1.w};
            bf16x8 ah, al;
            #pragma unroll
            for (int j = 0; j < 8; ++j) {
                __bf16 h = (__bf16)av[j];
                ah[j] = h;
                al[j] = (__bf16)(av[j] - (float)h);
            }
            #pragma unroll
            for (int nt = 0; nt < 8; ++nt) {
                int n = nt * 16 + lrow;
                int k8 = ks * 4 + lgrp;
                int addr = n * 128 + ((k8 ^ (n & 15)) << 3);
                bf16x8 bh = *(const bf16x8*)&sWhi[addr];
                bf16x8 bl = *(const bf16x8*)&sWlo[addr];
                acc[nt] = __builtin_amdgcn_mfma_f32_16x16x32_bf16(ah, bh, acc[nt], 0, 0, 0);
                acc[nt] = __builtin_amdgcn_mfma_f32_16x16x32_bf16(ah, bl, acc[nt], 0, 0, 0);
                acc[nt] = __builtin_amdgcn_mfma_f32_16x16x32_bf16(al, bh, acc[nt], 0, 0, 0);
            }
        }

        const int orow = base + w * 16 + lgrp * 4;
        #pragma unroll
        for (int r = 0; r < 4; ++r) {
            if (orow + r < M) {
                #pragma unroll
                for (int nt = 0; nt < 8; ++nt) {
                    float v = acc[nt][r] + bv[nt];
                    if (ACT) v = ssp(v);
                    C[(size_t)(orow + r) * 128 + nt * 16 + lrow] = v;
                }
            }
        }
    }
}

extern "C" void kernel_launch(void* const* d_in, const int* in_sizes, int n_in,
                              void* d_out, int out_size, void* d_ws, size_t ws_size,
                              hipStream_t stream) {
    const float* r   = (const float*)d_in[0];
    const float* e   = (const float*)d_in[1];
    const float* Wf2 = (const float*)d_in[2];
    const float* bf2 = (const float*)d_in[3];
    const float* Wa  = (const float*)d_in[4];
    const float* W1  = (const float*)d_in[5];
    const float* b1  = (const float*)d_in[6];
    const float* W2  = (const float*)d_in[7];
    const float* b2  = (const float*)d_in[8];
    const int*   a   = (const int*)d_in[9];

    float* out = (float*)d_out;

    // workspace layout (4B words)
    float*  buf0       = (float*)d_ws;                 // rf / y1 (6.4M words)
    int*    counts     = (int*)d_ws + 6400000;         // NBIN
    int*    row_ptr    = counts + NBIN;                // NBIN
    int*    cursor     = row_ptr + NBIN;               // NBIN
    int*    chunk_sums = cursor + NBIN;                // 128
    float2* ses        = (float2*)(chunk_sums + 128);  // NE packed (e, src)

    float* seg = out;   // d_out doubles as segment-sum buffer (fully overwritten)

    // CSR build
    hipMemsetAsync(counts, 0, NBIN * sizeof(int), stream);
    hist_kernel<<<1024, 256, 0, stream>>>(a, counts);
    scanA<<<NCH, 512, 0, stream>>>(counts, chunk_sums);
    scanB<<<1, 128, 0, stream>>>(chunk_sums);
    scanC<<<NCH, 512, 0, stream>>>(counts, chunk_sums, row_ptr, cursor);
    scatter_kernel<<<1024, 256, 0, stream>>>(a, e, cursor, ses);

    // rf = r @ Wa
    mfma_gemm<0, 0><<<391, 256, 0, stream>>>(r, Wa, nullptr, buf0, NA);

    // fused edge pipeline (balanced waves, batched gathers)
    edge_fused<<<EGRID, 256, 0, stream>>>(ses, row_ptr, Wf2, bf2, buf0, seg);

    // y1 = ssp(seg @ W1 + b1); out = y1 @ W2 + b2
    mfma_gemm<1, 1><<<391, 256, 0, stream>>>(seg, W1, b1, buf0, NA);
    mfma_gemm<0, 1><<<391, 256, 0, stream>>>(buf0, W2, b2, out, NA);
}

// Round 7
// 317.766 us; speedup vs baseline: 2.5489x; 1.1073x over previous
//
#include <hip/hip_runtime.h>
#include <hip/hip_bf16.h>
#include <math.h>

#define NA 50000
#define NE 800000
#define NBIN 50176            // NA rounded to 98*512
#define NCH 98
#define WPB 4                 // waves per block
#define EGRID 1024            // edge_fused blocks (4/CU)
#define NWAVES (EGRID * WPB)  // 4096 -> 12-13 dsts/wave
#define SCAT_BLKS 1024
#define RF_BLKS 391

typedef float f32x4 __attribute__((ext_vector_type(4)));
typedef __bf16 bf16x8 __attribute__((ext_vector_type(8)));

__device__ __forceinline__ float ssp(float x) {
    float sp = (x > 15.0f) ? x : log1pf(__expf(x));
    return sp - 0.69314718f;
}

// ---------------------------------------------------------------------------
// CSR build
// ---------------------------------------------------------------------------
__global__ __launch_bounds__(256) void hist_kernel(const int* __restrict__ a,
                                                   int* __restrict__ counts) {
    for (int i = blockIdx.x * 256 + threadIdx.x; i < NE; i += gridDim.x * 256) {
        int2 dp = ((const int2*)a)[i];
        atomicAdd(&counts[dp.x], 1);
    }
}

__global__ __launch_bounds__(512) void scanA(const int* __restrict__ counts,
                                             int* __restrict__ chunk_sums) {
    __shared__ int red[512];
    int t = threadIdx.x;
    red[t] = counts[blockIdx.x * 512 + t];
    __syncthreads();
    for (int off = 256; off > 0; off >>= 1) {
        if (t < off) red[t] += red[t + off];
        __syncthreads();
    }
    if (t == 0) chunk_sums[blockIdx.x] = red[0];
}

__global__ __launch_bounds__(128) void scanB(int* __restrict__ chunk_sums) {
    __shared__ int s[128];
    int t = threadIdx.x;
    int v = (t < NCH) ? chunk_sums[t] : 0;
    s[t] = v;
    __syncthreads();
    for (int off = 1; off < 128; off <<= 1) {
        int add = (t >= off) ? s[t - off] : 0;
        __syncthreads();
        s[t] += add;
        __syncthreads();
    }
    if (t < NCH) chunk_sums[t] = s[t] - v;
}

__global__ __launch_bounds__(512) void scanC(const int* __restrict__ counts,
                                             const int* __restrict__ chunk_sums,
                                             int* __restrict__ row_ptr,
                                             int* __restrict__ cursor) {
    __shared__ int s[512];
    int t = threadIdx.x;
    int i = blockIdx.x * 512 + t;
    int v = counts[i];
    s[t] = v;
    __syncthreads();
    for (int off = 1; off < 512; off <<= 1) {
        int add = (t >= off) ? s[t - off] : 0;
        __syncthreads();
        s[t] += add;
        __syncthreads();
    }
    int excl = s[t] - v + chunk_sums[blockIdx.x];
    row_ptr[i] = excl;
    cursor[i]  = excl;
}

// ---------------------------------------------------------------------------
// Dense GEMM body: C[M,128] = act(A[M,128] @ W[128,128] + b), hi/lo MFMA.
// ---------------------------------------------------------------------------
template<int ACT, int BIAS>
__device__ __forceinline__ void gemm_body(const float* __restrict__ A,
                                          const float* __restrict__ W,
                                          const float* __restrict__ b,
                                          float* __restrict__ C, int M,
                                          int blk, int gridn,
                                          __bf16* sWhi, __bf16* sWlo) {
    const int tid = threadIdx.x;
    {
        const float4* W4 = (const float4*)W;
        for (int i = tid; i < 128 * 128 / 4; i += 256) {
            float4 v = W4[i];
            #pragma unroll
            for (int q = 0; q < 4; ++q) {
                int idx = i * 4 + q;
                int k = idx >> 7, n = idx & 127;
                float x = ((const float*)&v)[q];
                __bf16 h = (__bf16)x;
                __bf16 l = (__bf16)(x - (float)h);
                int addr = n * 128 + (((k >> 3) ^ (n & 15)) << 3) + (k & 7);
                sWhi[addr] = h;
                sWlo[addr] = l;
            }
        }
    }
    __syncthreads();

    const int lane = tid & 63, w = tid >> 6;
    const int lrow = lane & 15, lgrp = lane >> 4;

    float bv[8];
    #pragma unroll
    for (int nt = 0; nt < 8; ++nt) bv[nt] = BIAS ? b[nt * 16 + lrow] : 0.0f;

    for (int base = blk * 64; base < M; base += gridn * 64) {
        const int row  = base + w * 16 + lrow;
        const int rowc = row < M ? row : M - 1;

        f32x4 acc[8];
        #pragma unroll
        for (int nt = 0; nt < 8; ++nt) acc[nt] = (f32x4){0.f, 0.f, 0.f, 0.f};

        #pragma unroll
        for (int ks = 0; ks < 4; ++ks) {
            int k0 = ks * 32 + lgrp * 8;
            float4 f0 = *(const float4*)&A[(size_t)rowc * 128 + k0];
            float4 f1 = *(const float4*)&A[(size_t)rowc * 128 + k0 + 4];
            float av[8] = {f0.x, f0.y, f0.z, f0.w, f1.x, f1.y, f1.z, f1.w};
            bf16x8 ah, al;
            #pragma unroll
            for (int j = 0; j < 8; ++j) {
                __bf16 h = (__bf16)av[j];
                ah[j] = h;
                al[j] = (__bf16)(av[j] - (float)h);
            }
            #pragma unroll
            for (int nt = 0; nt < 8; ++nt) {
                int n = nt * 16 + lrow;
                int k8 = ks * 4 + lgrp;
                int addr = n * 128 + ((k8 ^ (n & 15)) << 3);
                bf16x8 bh = *(const bf16x8*)&sWhi[addr];
                bf16x8 bl = *(const bf16x8*)&sWlo[addr];
                acc[nt] = __builtin_amdgcn_mfma_f32_16x16x32_bf16(ah, bh, acc[nt], 0, 0, 0);
                acc[nt] = __builtin_amdgcn_mfma_f32_16x16x32_bf16(ah, bl, acc[nt], 0, 0, 0);
                acc[nt] = __builtin_amdgcn_mfma_f32_16x16x32_bf16(al, bh, acc[nt], 0, 0, 0);
            }
        }

        const int orow = base + w * 16 + lgrp * 4;
        #pragma unroll
        for (int r = 0; r < 4; ++r) {
            if (orow + r < M) {
                #pragma unroll
                for (int nt = 0; nt < 8; ++nt) {
                    float v = acc[nt][r] + bv[nt];
                    if (ACT) v = ssp(v);
                    C[(size_t)(orow + r) * 128 + nt * 16 + lrow] = v;
                }
            }
        }
    }
}

template<int ACT, int BIAS>
__global__ __launch_bounds__(256) void mfma_gemm(const float* __restrict__ A,
                                                 const float* __restrict__ W,
                                                 const float* __restrict__ b,
                                                 float* __restrict__ C, int M) {
    __shared__ __bf16 sWhi[128 * 128];
    __shared__ __bf16 sWlo[128 * 128];
    gemm_body<ACT, BIAS>(A, W, b, C, M, blockIdx.x, gridDim.x, sWhi, sWlo);
}

// ---------------------------------------------------------------------------
// Fused: scatter (latency-bound) || rf = r @ Wa (MFMA-bound) via block split.
// Scatter packs (u16-quantized e)<<16 | u16 src -> 4B random store per edge.
// ---------------------------------------------------------------------------
__global__ __launch_bounds__(256) void scatter_rf(const int* __restrict__ a,
                                                  const float* __restrict__ e,
                                                  int* __restrict__ cursor,
                                                  uint32_t* __restrict__ sesq,
                                                  const float* __restrict__ r,
                                                  const float* __restrict__ Wa,
                                                  float* __restrict__ rf) {
    __shared__ __bf16 sWhi[128 * 128];
    __shared__ __bf16 sWlo[128 * 128];
    if (blockIdx.x < SCAT_BLKS) {
        for (int i = blockIdx.x * 256 + threadIdx.x; i < NE; i += SCAT_BLKS * 256) {
            int2 dp = ((const int2*)a)[i];
            int pos = atomicAdd(&cursor[dp.x], 1);
            uint32_t eq = (uint32_t)(e[i] * 13107.0f + 0.5f);   // 65535/5
            sesq[pos] = (eq << 16) | (uint32_t)dp.y;
        }
    } else {
        gemm_body<0, 0>(r, Wa, nullptr, rf, NA, blockIdx.x - SCAT_BLKS, RF_BLKS,
                        sWhi, sWlo);
    }
}

// ---------------------------------------------------------------------------
// Fused edge pipeline v3: 32-edge MFMA chunks, 16-edge bounce/consume halves.
// LDS ~33KB -> 4 blocks/CU (16 waves). Consume: 16 rf-row gathers + 16 LDS
// reads fully batched (one latency exposure per half). No atomics/barriers.
// ---------------------------------------------------------------------------
__global__ __launch_bounds__(256, 4) void edge_fused(const uint32_t* __restrict__ sesq,
                                                     const int* __restrict__ row_ptr,
                                                     const float* __restrict__ Wf2,
                                                     const float* __restrict__ bf2,
                                                     const float* __restrict__ rf,
                                                     float* __restrict__ seg) {
    __shared__ __bf16 sWf[128 * 64];       // 16KB: Wf2^T bf16, k8 XOR swizzle
    __shared__ __bf16 sP[WPB][16 * 128];   // 4KB/wave bounce [e][f], XOR granules
    __shared__ float  sse[WPB][32];
    __shared__ int    sssrc[WPB][32];
    __shared__ int    ssrp[WPB][16];

    const int tid  = threadIdx.x;
    const int lane = tid & 63, w = tid >> 6;
    const int lrow = lane & 15, lgrp = lane >> 4;

    {
        const float4* W4 = (const float4*)Wf2;
        for (int i = tid; i < 64 * 128 / 4; i += 256) {
            float4 v = W4[i];
            #pragma unroll
            for (int q = 0; q < 4; ++q) {
                int idx = i * 4 + q;
                int k = idx >> 7, n = idx & 127;
                float x = ((const float*)&v)[q];
                int addr = n * 64 + (((k >> 3) ^ (n & 7)) << 3) + (k & 7);
                sWf[addr] = (__bf16)x;
            }
        }
    }
    const int wi      = blockIdx.x * WPB + w;
    const int d_start = (int)(((long long)wi * NA) / NWAVES);
    const int d_end   = (int)(((long long)(wi + 1) * NA) / NWAVES);
    const int dcount  = d_end - d_start;            // 12 or 13
    if (lane <= dcount)     ssrp[w][lane] = row_ptr[d_start + lane];
    if (lane == dcount + 1) ssrp[w][lane] = 0x7FFFFFFF;
    __syncthreads();

    float bv[8];
    #pragma unroll
    for (int nt = 0; nt < 8; ++nt) bv[nt] = bf2[nt * 16 + lrow];

    const float coeff = -0.5f * (63.0f / 5.0f) * (63.0f / 5.0f);
    float* sse_w  = sse[w];
    int*   ssrc_w = sssrc[w];
    int*   srp_w  = ssrp[w];
    __bf16* myP   = sP[w];
    const uint32_t* myPu = (const uint32_t*)myP;

    const int rp0 = srp_w[0], rend = srp_w[dcount];
    int ld = 0;
    int nextb = srp_w[1];
    float racc0 = 0.0f, racc1 = 0.0f;

    for (int p = rp0; p < rend; p += 32) {
        const int cnt = (rend - p < 32) ? (rend - p) : 32;
        if (lane < 32) {
            uint32_t u = (lane < cnt) ? sesq[p + lane] : 0u;
            sse_w[lane]  = (float)(u >> 16) * (1.0f / 13107.0f);
            ssrc_w[lane] = (int)(u & 0xFFFFu);
        }
        __builtin_amdgcn_wave_barrier();

        #pragma unroll
        for (int mt = 0; mt < 2; ++mt) {
            if (mt * 16 >= cnt) break;          // wave-uniform

            // gaussian A fragments for this 16-edge tile (hi/lo of g)
            float ev = sse_w[mt * 16 + lrow];
            bf16x8 ah[2], al[2];
            #pragma unroll
            for (int ks = 0; ks < 2; ++ks) {
                #pragma unroll
                for (int j = 0; j < 8; ++j) {
                    int k = ks * 32 + lgrp * 8 + j;
                    float dd = ev - (5.0f / 63.0f) * (float)k;
                    float g = __expf(coeff * dd * dd);
                    __bf16 h = (__bf16)g;
                    ah[ks][j] = h;
                    al[ks][j] = (__bf16)(g - (float)h);
                }
            }

            // filter MFMA (2-term hi/lo of g x bf16 W)
            f32x4 c[8];
            #pragma unroll
            for (int nt = 0; nt < 8; ++nt) c[nt] = (f32x4){0.f, 0.f, 0.f, 0.f};
            #pragma unroll
            for (int ks = 0; ks < 2; ++ks) {
                #pragma unroll
                for (int nt = 0; nt < 8; ++nt) {
                    int n = nt * 16 + lrow;
                    int addr = n * 64 + (((ks * 4 + lgrp) ^ (n & 7)) << 3);
                    bf16x8 bh = *(const bf16x8*)&sWf[addr];
                    c[nt] = __builtin_amdgcn_mfma_f32_16x16x32_bf16(ah[ks], bh, c[nt], 0, 0, 0);
                    c[nt] = __builtin_amdgcn_mfma_f32_16x16x32_bf16(al[ks], bh, c[nt], 0, 0, 0);
                }
            }

            // bounce: bias + bf16 pack into wave-private LDS
            #pragma unroll
            for (int nt = 0; nt < 8; ++nt) {
                int f = nt * 16 + lrow;
                #pragma unroll
                for (int r = 0; r < 4; ++r) {
                    int e2 = lgrp * 4 + r;
                    float v = c[nt][r] + bv[nt];
                    myP[e2 * 128 + (((f >> 3) ^ (e2 & 7)) << 3) + (f & 7)] = (__bf16)v;
                }
            }
            __builtin_amdgcn_wave_barrier();

            // fully-batched consume: 16 rf-row gathers + 16 LDS reads in flight
            float2   rv[16];
            uint32_t uu[16];
            #pragma unroll
            for (int j = 0; j < 16; ++j) {
                int src = ssrc_w[mt * 16 + j];
                rv[j] = *(const float2*)&rf[(size_t)src * 128 + lane * 2];
                uu[j] = myPu[j * 64 + (((lane >> 2) ^ (j & 7)) << 2) + (lane & 3)];
            }
            #pragma unroll
            for (int j = 0; j < 16; ++j) {
                int gj = p + mt * 16 + j;
                if (gj < rend) {                       // wave-uniform
                    while (gj >= nextb) {              // wave-uniform
                        float2 st; st.x = racc0; st.y = racc1;
                        *(float2*)&seg[(size_t)(d_start + ld) * 128 + lane * 2] = st;
                        racc0 = 0.0f; racc1 = 0.0f;
                        ++ld;
                        nextb = srp_w[ld + 1];
                    }
                    racc0 = fmaf(rv[j].x, __uint_as_float(uu[j] << 16), racc0);
                    racc1 = fmaf(rv[j].y, __uint_as_float(uu[j] & 0xFFFF0000u), racc1);
                }
            }
            __builtin_amdgcn_wave_barrier();           // before myP reuse
        }
    }
    // flush remaining dsts (incl. trailing empty ones)
    while (ld < dcount) {
        float2 st; st.x = racc0; st.y = racc1;
        *(float2*)&seg[(size_t)(d_start + ld) * 128 + lane * 2] = st;
        racc0 = 0.0f; racc1 = 0.0f;
        ++ld;
    }
}

extern "C" void kernel_launch(void* const* d_in, const int* in_sizes, int n_in,
                              void* d_out, int out_size, void* d_ws, size_t ws_size,
                              hipStream_t stream) {
    const float* r   = (const float*)d_in[0];
    const float* e   = (const float*)d_in[1];
    const float* Wf2 = (const float*)d_in[2];
    const float* bf2 = (const float*)d_in[3];
    const float* Wa  = (const float*)d_in[4];
    const float* W1  = (const float*)d_in[5];
    const float* b1  = (const float*)d_in[6];
    const float* W2  = (const float*)d_in[7];
    const float* b2  = (const float*)d_in[8];
    const int*   a   = (const int*)d_in[9];

    float* out = (float*)d_out;

    // workspace layout (4B words)
    float*    buf0       = (float*)d_ws;                 // rf / y1 (6.4M words)
    int*      counts     = (int*)d_ws + 6400000;         // NBIN
    int*      row_ptr    = counts + NBIN;                // NBIN
    int*      cursor     = row_ptr + NBIN;               // NBIN
    int*      chunk_sums = cursor + NBIN;                // 128
    uint32_t* sesq       = (uint32_t*)(chunk_sums + 128);// NE packed u16:u16

    float* seg = out;   // d_out doubles as segment-sum buffer (fully overwritten)

    // CSR build
    hipMemsetAsync(counts, 0, NBIN * sizeof(int), stream);
    hist_kernel<<<1024, 256, 0, stream>>>(a, counts);
    scanA<<<NCH, 512, 0, stream>>>(counts, chunk_sums);
    scanB<<<1, 128, 0, stream>>>(chunk_sums);
    scanC<<<NCH, 512, 0, stream>>>(counts, chunk_sums, row_ptr, cursor);

    // scatter (latency-bound) overlapped with rf = r @ Wa (MFMA-bound)
    scatter_rf<<<SCAT_BLKS + RF_BLKS, 256, 0, stream>>>(a, e, cursor, sesq,
                                                        r, Wa, buf0);

    // fused edge pipeline
    edge_fused<<<EGRID, 256, 0, stream>>>(sesq, row_ptr, Wf2, bf2, buf0, seg);

    // y1 = ssp(seg @ W1 + b1); out = y1 @ W2 + b2
    mfma_gemm<1, 1><<<391, 256, 0, stream>>>(seg, W1, b1, buf0, NA);
    mfma_gemm<0, 1><<<391, 256, 0, stream>>>(buf0, W2, b2, out, NA);
}

// Round 8
// 302.715 us; speedup vs baseline: 2.6756x; 1.0497x over previous
//
#include <hip/hip_runtime.h>
#include <hip/hip_bf16.h>
#include <math.h>

#define NA 50000
#define NE 800000
#define NBIN 50176            // NA rounded to 98*512
#define NCH 98
#define WPB 4                 // waves per block
#define EGRID 1024            // edge_fused blocks (4/CU)
#define NWAVES (EGRID * WPB)  // 4096 -> 12-13 dsts/wave
#define SCAT_BLKS 1024
#define RF_BLKS 391           // half of 782 tiles per overlap kernel

typedef float f32x4 __attribute__((ext_vector_type(4)));
typedef __bf16 bf16x8 __attribute__((ext_vector_type(8)));

__device__ __forceinline__ float ssp(float x) {
    float sp = (x > 15.0f) ? x : log1pf(__expf(x));
    return sp - 0.69314718f;
}

// ---------------------------------------------------------------------------
// CSR scans
// ---------------------------------------------------------------------------
__global__ __launch_bounds__(512) void scanA(const int* __restrict__ counts,
                                             int* __restrict__ chunk_sums) {
    __shared__ int red[512];
    int t = threadIdx.x;
    red[t] = counts[blockIdx.x * 512 + t];
    __syncthreads();
    for (int off = 256; off > 0; off >>= 1) {
        if (t < off) red[t] += red[t + off];
        __syncthreads();
    }
    if (t == 0) chunk_sums[blockIdx.x] = red[0];
}

__global__ __launch_bounds__(128) void scanB(int* __restrict__ chunk_sums) {
    __shared__ int s[128];
    int t = threadIdx.x;
    int v = (t < NCH) ? chunk_sums[t] : 0;
    s[t] = v;
    __syncthreads();
    for (int off = 1; off < 128; off <<= 1) {
        int add = (t >= off) ? s[t - off] : 0;
        __syncthreads();
        s[t] += add;
        __syncthreads();
    }
    if (t < NCH) chunk_sums[t] = s[t] - v;
}

__global__ __launch_bounds__(512) void scanC(const int* __restrict__ counts,
                                             const int* __restrict__ chunk_sums,
                                             int* __restrict__ row_ptr,
                                             int* __restrict__ cursor) {
    __shared__ int s[512];
    int t = threadIdx.x;
    int i = blockIdx.x * 512 + t;
    int v = counts[i];
    s[t] = v;
    __syncthreads();
    for (int off = 1; off < 512; off <<= 1) {
        int add = (t >= off) ? s[t - off] : 0;
        __syncthreads();
        s[t] += add;
        __syncthreads();
    }
    int excl = s[t] - v + chunk_sums[blockIdx.x];
    row_ptr[i] = excl;
    cursor[i]  = excl;
}

// ---------------------------------------------------------------------------
// Dense GEMM body: C[M,128] = act(A[M,128] @ W[128,128] + b), hi/lo MFMA.
// OB16: store output as packed bf16 (for rf), else fp32.
// ---------------------------------------------------------------------------
template<int ACT, int BIAS, int OB16>
__device__ __forceinline__ void gemm_body(const float* __restrict__ A,
                                          const float* __restrict__ W,
                                          const float* __restrict__ b,
                                          void* __restrict__ C, int M,
                                          int blk, int gridn,
                                          __bf16* sWhi, __bf16* sWlo) {
    const int tid = threadIdx.x;
    {
        const float4* W4 = (const float4*)W;
        for (int i = tid; i < 128 * 128 / 4; i += 256) {
            float4 v = W4[i];
            #pragma unroll
            for (int q = 0; q < 4; ++q) {
                int idx = i * 4 + q;
                int k = idx >> 7, n = idx & 127;
                float x = ((const float*)&v)[q];
                __bf16 h = (__bf16)x;
                __bf16 l = (__bf16)(x - (float)h);
                int addr = n * 128 + (((k >> 3) ^ (n & 15)) << 3) + (k & 7);
                sWhi[addr] = h;
                sWlo[addr] = l;
            }
        }
    }
    __syncthreads();

    const int lane = tid & 63, w = tid >> 6;
    const int lrow = lane & 15, lgrp = lane >> 4;

    float bv[8];
    #pragma unroll
    for (int nt = 0; nt < 8; ++nt) bv[nt] = BIAS ? b[nt * 16 + lrow] : 0.0f;

    for (int base = blk * 64; base < M; base += gridn * 64) {
        const int row  = base + w * 16 + lrow;
        const int rowc = row < M ? row : M - 1;

        f32x4 acc[8];
        #pragma unroll
        for (int nt = 0; nt < 8; ++nt) acc[nt] = (f32x4){0.f, 0.f, 0.f, 0.f};

        #pragma unroll
        for (int ks = 0; ks < 4; ++ks) {
            int k0 = ks * 32 + lgrp * 8;
            float4 f0 = *(const float4*)&A[(size_t)rowc * 128 + k0];
            float4 f1 = *(const float4*)&A[(size_t)rowc * 128 + k0 + 4];
            float av[8] = {f0.x, f0.y, f0.z, f0.w, f1.x, f1.y, f1.z, f1.w};
            bf16x8 ah, al;
            #pragma unroll
            for (int j = 0; j < 8; ++j) {
                __bf16 h = (__bf16)av[j];
                ah[j] = h;
                al[j] = (__bf16)(av[j] - (float)h);
            }
            #pragma unroll
            for (int nt = 0; nt < 8; ++nt) {
                int n = nt * 16 + lrow;
                int k8 = ks * 4 + lgrp;
                int addr = n * 128 + ((k8 ^ (n & 15)) << 3);
                bf16x8 bh = *(const bf16x8*)&sWhi[addr];
                bf16x8 bl = *(const bf16x8*)&sWlo[addr];
                acc[nt] = __builtin_amdgcn_mfma_f32_16x16x32_bf16(ah, bh, acc[nt], 0, 0, 0);
                acc[nt] = __builtin_amdgcn_mfma_f32_16x16x32_bf16(ah, bl, acc[nt], 0, 0, 0);
                acc[nt] = __builtin_amdgcn_mfma_f32_16x16x32_bf16(al, bh, acc[nt], 0, 0, 0);
            }
        }

        const int orow = base + w * 16 + lgrp * 4;
        #pragma unroll
        for (int r = 0; r < 4; ++r) {
            if (orow + r < M) {
                #pragma unroll
                for (int nt = 0; nt < 8; ++nt) {
                    float v = acc[nt][r] + bv[nt];
                    if (ACT) v = ssp(v);
                    if (OB16) {
                        ((__hip_bfloat16*)C)[(size_t)(orow + r) * 128 + nt * 16 + lrow] =
                            __float2bfloat16(v);
                    } else {
                        ((float*)C)[(size_t)(orow + r) * 128 + nt * 16 + lrow] = v;
                    }
                }
            }
        }
    }
}

template<int ACT, int BIAS>
__global__ __launch_bounds__(256) void mfma_gemm(const float* __restrict__ A,
                                                 const float* __restrict__ W,
                                                 const float* __restrict__ b,
                                                 float* __restrict__ C, int M) {
    __shared__ __bf16 sWhi[128 * 128];
    __shared__ __bf16 sWlo[128 * 128];
    gemm_body<ACT, BIAS, 0>(A, W, b, C, M, blockIdx.x, gridDim.x, sWhi, sWlo);
}

// ---------------------------------------------------------------------------
// Overlap kernel 1: hist (latency/atomic-bound) || rf-GEMM tiles [0,391)
// ---------------------------------------------------------------------------
__global__ __launch_bounds__(256) void hist_rf(const int* __restrict__ a,
                                               int* __restrict__ counts,
                                               const float* __restrict__ r,
                                               const float* __restrict__ Wa,
                                               void* __restrict__ rfb) {
    __shared__ __bf16 sWhi[128 * 128];
    __shared__ __bf16 sWlo[128 * 128];
    if (blockIdx.x < SCAT_BLKS) {
        for (int i = blockIdx.x * 256 + threadIdx.x; i < NE; i += SCAT_BLKS * 256) {
            int2 dp = ((const int2*)a)[i];
            atomicAdd(&counts[dp.x], 1);
        }
    } else {
        gemm_body<0, 0, 1>(r, Wa, nullptr, rfb, NA, blockIdx.x - SCAT_BLKS,
                           2 * RF_BLKS, sWhi, sWlo);
    }
}

// ---------------------------------------------------------------------------
// Overlap kernel 2: scatter (latency-bound) || rf-GEMM tiles [391,782)
// Scatter packs (u16-quantized e)<<16 | u16 src -> 4B random store per edge.
// ---------------------------------------------------------------------------
__global__ __launch_bounds__(256) void scatter_rf(const int* __restrict__ a,
                                                  const float* __restrict__ e,
                                                  int* __restrict__ cursor,
                                                  uint32_t* __restrict__ sesq,
                                                  const float* __restrict__ r,
                                                  const float* __restrict__ Wa,
                                                  void* __restrict__ rfb) {
    __shared__ __bf16 sWhi[128 * 128];
    __shared__ __bf16 sWlo[128 * 128];
    if (blockIdx.x < SCAT_BLKS) {
        for (int i = blockIdx.x * 256 + threadIdx.x; i < NE; i += SCAT_BLKS * 256) {
            int2 dp = ((const int2*)a)[i];
            int pos = atomicAdd(&cursor[dp.x], 1);
            uint32_t eq = (uint32_t)(e[i] * 13107.0f + 0.5f);   // 65535/5
            sesq[pos] = (eq << 16) | (uint32_t)dp.y;
        }
    } else {
        gemm_body<0, 0, 1>(r, Wa, nullptr, rfb, NA,
                           blockIdx.x - SCAT_BLKS + RF_BLKS, 2 * RF_BLKS,
                           sWhi, sWlo);
    }
}

// ---------------------------------------------------------------------------
// Fused edge pipeline: 32-edge MFMA chunks, 16-edge bounce/consume halves.
// rf is packed bf16 (u32 = 2 feats/lane) -> half the gather bytes.
// ---------------------------------------------------------------------------
__global__ __launch_bounds__(256, 4) void edge_fused(const uint32_t* __restrict__ sesq,
                                                     const int* __restrict__ row_ptr,
                                                     const float* __restrict__ Wf2,
                                                     const float* __restrict__ bf2,
                                                     const uint32_t* __restrict__ rfb,
                                                     float* __restrict__ seg) {
    __shared__ __bf16 sWf[128 * 64];       // 16KB: Wf2^T bf16, k8 XOR swizzle
    __shared__ __bf16 sP[WPB][16 * 128];   // 4KB/wave bounce [e][f], XOR granules
    __shared__ float  sse[WPB][32];
    __shared__ int    sssrc[WPB][32];
    __shared__ int    ssrp[WPB][16];

    const int tid  = threadIdx.x;
    const int lane = tid & 63, w = tid >> 6;
    const int lrow = lane & 15, lgrp = lane >> 4;

    {
        const float4* W4 = (const float4*)Wf2;
        for (int i = tid; i < 64 * 128 / 4; i += 256) {
            float4 v = W4[i];
            #pragma unroll
            for (int q = 0; q < 4; ++q) {
                int idx = i * 4 + q;
                int k = idx >> 7, n = idx & 127;
                float x = ((const float*)&v)[q];
                int addr = n * 64 + (((k >> 3) ^ (n & 7)) << 3) + (k & 7);
                sWf[addr] = (__bf16)x;
            }
        }
    }
    const int wi      = blockIdx.x * WPB + w;
    const int d_start = (int)(((long long)wi * NA) / NWAVES);
    const int d_end   = (int)(((long long)(wi + 1) * NA) / NWAVES);
    const int dcount  = d_end - d_start;            // 12 or 13
    if (lane <= dcount)     ssrp[w][lane] = row_ptr[d_start + lane];
    if (lane == dcount + 1) ssrp[w][lane] = 0x7FFFFFFF;
    __syncthreads();

    float bv[8];
    #pragma unroll
    for (int nt = 0; nt < 8; ++nt) bv[nt] = bf2[nt * 16 + lrow];

    const float coeff = -0.5f * (63.0f / 5.0f) * (63.0f / 5.0f);
    float* sse_w  = sse[w];
    int*   ssrc_w = sssrc[w];
    int*   srp_w  = ssrp[w];
    __bf16* myP   = sP[w];
    const uint32_t* myPu = (const uint32_t*)myP;

    const int rp0 = srp_w[0], rend = srp_w[dcount];
    int ld = 0;
    int nextb = srp_w[1];
    float racc0 = 0.0f, racc1 = 0.0f;

    for (int p = rp0; p < rend; p += 32) {
        const int cnt = (rend - p < 32) ? (rend - p) : 32;
        if (lane < 32) {
            uint32_t u = (lane < cnt) ? sesq[p + lane] : 0u;
            sse_w[lane]  = (float)(u >> 16) * (1.0f / 13107.0f);
            ssrc_w[lane] = (int)(u & 0xFFFFu);
        }
        __builtin_amdgcn_wave_barrier();

        #pragma unroll
        for (int mt = 0; mt < 2; ++mt) {
            if (mt * 16 >= cnt) break;          // wave-uniform

            // gaussian A fragments for this 16-edge tile (hi/lo of g)
            float ev = sse_w[mt * 16 + lrow];
            bf16x8 ah[2], al[2];
            #pragma unroll
            for (int ks = 0; ks < 2; ++ks) {
                #pragma unroll
                for (int j = 0; j < 8; ++j) {
                    int k = ks * 32 + lgrp * 8 + j;
                    float dd = ev - (5.0f / 63.0f) * (float)k;
                    float g = __expf(coeff * dd * dd);
                    __bf16 h = (__bf16)g;
                    ah[ks][j] = h;
                    al[ks][j] = (__bf16)(g - (float)h);
                }
            }

            // filter MFMA (2-term hi/lo of g x bf16 W)
            f32x4 c[8];
            #pragma unroll
            for (int nt = 0; nt < 8; ++nt) c[nt] = (f32x4){0.f, 0.f, 0.f, 0.f};
            #pragma unroll
            for (int ks = 0; ks < 2; ++ks) {
                #pragma unroll
                for (int nt = 0; nt < 8; ++nt) {
                    int n = nt * 16 + lrow;
                    int addr = n * 64 + (((ks * 4 + lgrp) ^ (n & 7)) << 3);
                    bf16x8 bh = *(const bf16x8*)&sWf[addr];
                    c[nt] = __builtin_amdgcn_mfma_f32_16x16x32_bf16(ah[ks], bh, c[nt], 0, 0, 0);
                    c[nt] = __builtin_amdgcn_mfma_f32_16x16x32_bf16(al[ks], bh, c[nt], 0, 0, 0);
                }
            }

            // bounce: bias + bf16 pack into wave-private LDS
            #pragma unroll
            for (int nt = 0; nt < 8; ++nt) {
                int f = nt * 16 + lrow;
                #pragma unroll
                for (int r = 0; r < 4; ++r) {
                    int e2 = lgrp * 4 + r;
                    float v = c[nt][r] + bv[nt];
                    myP[e2 * 128 + (((f >> 3) ^ (e2 & 7)) << 3) + (f & 7)] = (__bf16)v;
                }
            }
            __builtin_amdgcn_wave_barrier();

            // fully-batched consume: 16 bf16-rf gathers + 16 LDS reads in flight
            uint32_t rw[16];
            uint32_t uu[16];
            #pragma unroll
            for (int j = 0; j < 16; ++j) {
                int src = ssrc_w[mt * 16 + j];
                rw[j] = rfb[(size_t)src * 64 + lane];
                uu[j] = myPu[j * 64 + (((lane >> 2) ^ (j & 7)) << 2) + (lane & 3)];
            }
            #pragma unroll
            for (int j = 0; j < 16; ++j) {
                int gj = p + mt * 16 + j;
                if (gj < rend) {                       // wave-uniform
                    while (gj >= nextb) {              // wave-uniform
                        float2 st; st.x = racc0; st.y = racc1;
                        *(float2*)&seg[(size_t)(d_start + ld) * 128 + lane * 2] = st;
                        racc0 = 0.0f; racc1 = 0.0f;
                        ++ld;
                        nextb = srp_w[ld + 1];
                    }
                    racc0 = fmaf(__uint_as_float(rw[j] << 16),
                                 __uint_as_float(uu[j] << 16), racc0);
                    racc1 = fmaf(__uint_as_float(rw[j] & 0xFFFF0000u),
                                 __uint_as_float(uu[j] & 0xFFFF0000u), racc1);
                }
            }
            __builtin_amdgcn_wave_barrier();           // before myP reuse
        }
    }
    // flush remaining dsts (incl. trailing empty ones)
    while (ld < dcount) {
        float2 st; st.x = racc0; st.y = racc1;
        *(float2*)&seg[(size_t)(d_start + ld) * 128 + lane * 2] = st;
        racc0 = 0.0f; racc1 = 0.0f;
        ++ld;
    }
}

extern "C" void kernel_launch(void* const* d_in, const int* in_sizes, int n_in,
                              void* d_out, int out_size, void* d_ws, size_t ws_size,
                              hipStream_t stream) {
    const float* r   = (const float*)d_in[0];
    const float* e   = (const float*)d_in[1];
    const float* Wf2 = (const float*)d_in[2];
    const float* bf2 = (const float*)d_in[3];
    const float* Wa  = (const float*)d_in[4];
    const float* W1  = (const float*)d_in[5];
    const float* b1  = (const float*)d_in[6];
    const float* W2  = (const float*)d_in[7];
    const float* b2  = (const float*)d_in[8];
    const int*   a   = (const int*)d_in[9];

    float* out = (float*)d_out;

    // workspace layout (4B words). rfb (bf16 rf, 3.2M words) aliases buf0:
    // rfb is dead once edge_fused completes; y1 (buf0) is written after.
    float*    buf0       = (float*)d_ws;                 // y1 (6.4M words)
    uint32_t* rfb        = (uint32_t*)d_ws;              // rf bf16 (3.2M words)
    int*      counts     = (int*)d_ws + 6400000;         // NBIN
    int*      row_ptr    = counts + NBIN;                // NBIN
    int*      cursor     = row_ptr + NBIN;               // NBIN
    int*      chunk_sums = cursor + NBIN;                // 128
    uint32_t* sesq       = (uint32_t*)(chunk_sums + 128);// NE packed u16:u16

    float* seg = out;   // d_out doubles as segment-sum buffer (fully overwritten)

    hipMemsetAsync(counts, 0, NBIN * sizeof(int), stream);

    // hist (atomic-bound) || rf-GEMM first half
    hist_rf<<<SCAT_BLKS + RF_BLKS, 256, 0, stream>>>(a, counts, r, Wa, rfb);
    scanA<<<NCH, 512, 0, stream>>>(counts, chunk_sums);
    scanB<<<1, 128, 0, stream>>>(chunk_sums);
    scanC<<<NCH, 512, 0, stream>>>(counts, chunk_sums, row_ptr, cursor);
    // scatter (latency-bound) || rf-GEMM second half
    scatter_rf<<<SCAT_BLKS + RF_BLKS, 256, 0, stream>>>(a, e, cursor, sesq,
                                                        r, Wa, rfb);

    // fused edge pipeline
    edge_fused<<<EGRID, 256, 0, stream>>>(sesq, row_ptr, Wf2, bf2, rfb, seg);

    // y1 = ssp(seg @ W1 + b1); out = y1 @ W2 + b2
    mfma_gemm<1, 1><<<391, 256, 0, stream>>>(seg, W1, b1, buf0, NA);
    mfma_gemm<0, 1><<<391, 256, 0, stream>>>(buf0, W2, b2, out, NA);
}

// Round 9
// 235.576 us; speedup vs baseline: 3.4381x; 1.2850x over previous
//
#include <hip/hip_runtime.h>
#include <hip/hip_bf16.h>
#include <math.h>

#define NA 50000
#define NE 800000
#define NBIN 50176            // NA rounded to 98*512
#define NCH 98
#define WPB 4                 // waves per block
#define EGRID 1024            // edge_fused blocks (4/CU)
#define NWAVES (EGRID * WPB)  // 4096 -> 12-13 dsts/wave
#define SCAT_BLKS 1024
#define RF_BLKS 391           // half of 782 tiles per overlap kernel

typedef float f32x4 __attribute__((ext_vector_type(4)));
typedef __bf16 bf16x8 __attribute__((ext_vector_type(8)));

__device__ __forceinline__ float ssp(float x) {
    float sp = (x > 15.0f) ? x : log1pf(__expf(x));
    return sp - 0.69314718f;
}

// ---------------------------------------------------------------------------
// Pack weights once per launch into MFMA-B-fragment order (hi/lo bf16).
// gemm layout: addr = n*128 + (((k>>3)^(n&15))<<3) + (k&7)   (128x128)
// edge layout: addr = n*64  + (((k>>3)^(n&7 ))<<3) + (k&7)   (64x128, single)
// ---------------------------------------------------------------------------
__global__ __launch_bounds__(256) void pack_weights(const float* __restrict__ Wa,
                                                    const float* __restrict__ W1,
                                                    const float* __restrict__ W2,
                                                    const float* __restrict__ Wf2,
                                                    __bf16* __restrict__ pWaH, __bf16* __restrict__ pWaL,
                                                    __bf16* __restrict__ pW1H, __bf16* __restrict__ pW1L,
                                                    __bf16* __restrict__ pW2H, __bf16* __restrict__ pW2L,
                                                    __bf16* __restrict__ pWf) {
    const int t = blockIdx.x * 256 + threadIdx.x;
    const int stride = gridDim.x * 256;
    for (int i = t; i < 16384; i += stride) {
        int k = i >> 7, n = i & 127;
        int addr = n * 128 + (((k >> 3) ^ (n & 15)) << 3) + (k & 7);
        float v; __bf16 h;
        v = Wa[i]; h = (__bf16)v; pWaH[addr] = h; pWaL[addr] = (__bf16)(v - (float)h);
        v = W1[i]; h = (__bf16)v; pW1H[addr] = h; pW1L[addr] = (__bf16)(v - (float)h);
        v = W2[i]; h = (__bf16)v; pW2H[addr] = h; pW2L[addr] = (__bf16)(v - (float)h);
    }
    for (int i = t; i < 8192; i += stride) {
        int k = i >> 7, n = i & 127;
        int addr = n * 64 + (((k >> 3) ^ (n & 7)) << 3) + (k & 7);
        pWf[addr] = (__bf16)Wf2[i];
    }
}

// ---------------------------------------------------------------------------
// CSR scans
// ---------------------------------------------------------------------------
__global__ __launch_bounds__(512) void scanA(const int* __restrict__ counts,
                                             int* __restrict__ chunk_sums) {
    __shared__ int red[512];
    int t = threadIdx.x;
    red[t] = counts[blockIdx.x * 512 + t];
    __syncthreads();
    for (int off = 256; off > 0; off >>= 1) {
        if (t < off) red[t] += red[t + off];
        __syncthreads();
    }
    if (t == 0) chunk_sums[blockIdx.x] = red[0];
}

__global__ __launch_bounds__(128) void scanB(int* __restrict__ chunk_sums) {
    __shared__ int s[128];
    int t = threadIdx.x;
    int v = (t < NCH) ? chunk_sums[t] : 0;
    s[t] = v;
    __syncthreads();
    for (int off = 1; off < 128; off <<= 1) {
        int add = (t >= off) ? s[t - off] : 0;
        __syncthreads();
        s[t] += add;
        __syncthreads();
    }
    if (t < NCH) chunk_sums[t] = s[t] - v;
}

__global__ __launch_bounds__(512) void scanC(const int* __restrict__ counts,
                                             const int* __restrict__ chunk_sums,
                                             int* __restrict__ row_ptr,
                                             int* __restrict__ cursor) {
    __shared__ int s[512];
    int t = threadIdx.x;
    int i = blockIdx.x * 512 + t;
    int v = counts[i];
    s[t] = v;
    __syncthreads();
    for (int off = 1; off < 512; off <<= 1) {
        int add = (t >= off) ? s[t - off] : 0;
        __syncthreads();
        s[t] += add;
        __syncthreads();
    }
    int excl = s[t] - v + chunk_sums[blockIdx.x];
    row_ptr[i] = excl;
    cursor[i]  = excl;
}

// ---------------------------------------------------------------------------
// rf GEMM body with pre-packed weights: staging = straight 16B copies.
// Output packed bf16 (2 feats per u32).
// ---------------------------------------------------------------------------
__device__ __forceinline__ void rf_gemm_packed(const float* __restrict__ A,
                                               const __bf16* __restrict__ pWh,
                                               const __bf16* __restrict__ pWl,
                                               void* __restrict__ C, int M,
                                               int blk, int gridn,
                                               __bf16* sWhi, __bf16* sWlo) {
    const int tid = threadIdx.x;
    {
        const uint4* ph = (const uint4*)pWh;
        const uint4* pl = (const uint4*)pWl;
        uint4* dh = (uint4*)sWhi;
        uint4* dl = (uint4*)sWlo;
        for (int i = tid; i < 2048; i += 256) { dh[i] = ph[i]; dl[i] = pl[i]; }
    }
    __syncthreads();

    const int lane = tid & 63, w = tid >> 6;
    const int lrow = lane & 15, lgrp = lane >> 4;

    for (int base = blk * 64; base < M; base += gridn * 64) {
        const int row  = base + w * 16 + lrow;
        const int rowc = row < M ? row : M - 1;

        f32x4 acc[8];
        #pragma unroll
        for (int nt = 0; nt < 8; ++nt) acc[nt] = (f32x4){0.f, 0.f, 0.f, 0.f};

        #pragma unroll
        for (int ks = 0; ks < 4; ++ks) {
            int k0 = ks * 32 + lgrp * 8;
            float4 f0 = *(const float4*)&A[(size_t)rowc * 128 + k0];
            float4 f1 = *(const float4*)&A[(size_t)rowc * 128 + k0 + 4];
            float av[8] = {f0.x, f0.y, f0.z, f0.w, f1.x, f1.y, f1.z, f1.w};
            bf16x8 ah, al;
            #pragma unroll
            for (int j = 0; j < 8; ++j) {
                __bf16 h = (__bf16)av[j];
                ah[j] = h;
                al[j] = (__bf16)(av[j] - (float)h);
            }
            #pragma unroll
            for (int nt = 0; nt < 8; ++nt) {
                int n = nt * 16 + lrow;
                int addr = n * 128 + (((ks * 4 + lgrp) ^ (n & 15)) << 3);
                bf16x8 bh = *(const bf16x8*)&sWhi[addr];
                bf16x8 bl = *(const bf16x8*)&sWlo[addr];
                acc[nt] = __builtin_amdgcn_mfma_f32_16x16x32_bf16(ah, bh, acc[nt], 0, 0, 0);
                acc[nt] = __builtin_amdgcn_mfma_f32_16x16x32_bf16(ah, bl, acc[nt], 0, 0, 0);
                acc[nt] = __builtin_amdgcn_mfma_f32_16x16x32_bf16(al, bh, acc[nt], 0, 0, 0);
            }
        }

        const int orow = base + w * 16 + lgrp * 4;
        #pragma unroll
        for (int r = 0; r < 4; ++r) {
            if (orow + r < M) {
                #pragma unroll
                for (int nt = 0; nt < 8; ++nt) {
                    ((__hip_bfloat16*)C)[(size_t)(orow + r) * 128 + nt * 16 + lrow] =
                        __float2bfloat16(acc[nt][r]);
                }
            }
        }
    }
}

// ---------------------------------------------------------------------------
// Overlap kernel 1: hist (atomic-bound) || rf-GEMM tiles [0,391)
// ---------------------------------------------------------------------------
__global__ __launch_bounds__(256) void hist_rf(const int* __restrict__ a,
                                               int* __restrict__ counts,
                                               const float* __restrict__ r,
                                               const __bf16* __restrict__ pWaH,
                                               const __bf16* __restrict__ pWaL,
                                               void* __restrict__ rfb) {
    __shared__ __bf16 sWhi[128 * 128];
    __shared__ __bf16 sWlo[128 * 128];
    if (blockIdx.x < SCAT_BLKS) {
        for (int i = blockIdx.x * 256 + threadIdx.x; i < NE; i += SCAT_BLKS * 256) {
            int2 dp = ((const int2*)a)[i];
            atomicAdd(&counts[dp.x], 1);
        }
    } else {
        rf_gemm_packed(r, pWaH, pWaL, rfb, NA, blockIdx.x - SCAT_BLKS,
                       2 * RF_BLKS, sWhi, sWlo);
    }
}

// ---------------------------------------------------------------------------
// Overlap kernel 2: scatter (latency-bound) || rf-GEMM tiles [391,782)
// ---------------------------------------------------------------------------
__global__ __launch_bounds__(256) void scatter_rf(const int* __restrict__ a,
                                                  const float* __restrict__ e,
                                                  int* __restrict__ cursor,
                                                  uint32_t* __restrict__ sesq,
                                                  const float* __restrict__ r,
                                                  const __bf16* __restrict__ pWaH,
                                                  const __bf16* __restrict__ pWaL,
                                                  void* __restrict__ rfb) {
    __shared__ __bf16 sWhi[128 * 128];
    __shared__ __bf16 sWlo[128 * 128];
    if (blockIdx.x < SCAT_BLKS) {
        for (int i = blockIdx.x * 256 + threadIdx.x; i < NE; i += SCAT_BLKS * 256) {
            int2 dp = ((const int2*)a)[i];
            int pos = atomicAdd(&cursor[dp.x], 1);
            uint32_t eq = (uint32_t)(e[i] * 13107.0f + 0.5f);   // 65535/5
            sesq[pos] = (eq << 16) | (uint32_t)dp.y;
        }
    } else {
        rf_gemm_packed(r, pWaH, pWaL, rfb, NA,
                       blockIdx.x - SCAT_BLKS + RF_BLKS, 2 * RF_BLKS,
                       sWhi, sWlo);
    }
}

// ---------------------------------------------------------------------------
// Fused edge pipeline: 32-edge MFMA chunks, 16-edge bounce/consume halves.
// Wf2 pre-packed bf16 -> staging is a straight copy.
// ---------------------------------------------------------------------------
__global__ __launch_bounds__(256, 4) void edge_fused(const uint32_t* __restrict__ sesq,
                                                     const int* __restrict__ row_ptr,
                                                     const __bf16* __restrict__ pWf,
                                                     const float* __restrict__ bf2,
                                                     const uint32_t* __restrict__ rfb,
                                                     float* __restrict__ seg) {
    __shared__ __bf16 sWf[128 * 64];       // 16KB: Wf2^T bf16, k8 XOR swizzle
    __shared__ __bf16 sP[WPB][16 * 128];   // 4KB/wave bounce [e][f], XOR granules
    __shared__ float  sse[WPB][32];
    __shared__ int    sssrc[WPB][32];
    __shared__ int    ssrp[WPB][16];

    const int tid  = threadIdx.x;
    const int lane = tid & 63, w = tid >> 6;
    const int lrow = lane & 15, lgrp = lane >> 4;

    {
        const uint4* p = (const uint4*)pWf;
        uint4* d = (uint4*)sWf;
        for (int i = tid; i < 1024; i += 256) d[i] = p[i];
    }
    const int wi      = blockIdx.x * WPB + w;
    const int d_start = (int)(((long long)wi * NA) / NWAVES);
    const int d_end   = (int)(((long long)(wi + 1) * NA) / NWAVES);
    const int dcount  = d_end - d_start;            // 12 or 13
    if (lane <= dcount)     ssrp[w][lane] = row_ptr[d_start + lane];
    if (lane == dcount + 1) ssrp[w][lane] = 0x7FFFFFFF;
    __syncthreads();

    float bv[8];
    #pragma unroll
    for (int nt = 0; nt < 8; ++nt) bv[nt] = bf2[nt * 16 + lrow];

    const float coeff = -0.5f * (63.0f / 5.0f) * (63.0f / 5.0f);
    float* sse_w  = sse[w];
    int*   ssrc_w = sssrc[w];
    int*   srp_w  = ssrp[w];
    __bf16* myP   = sP[w];
    const uint32_t* myPu = (const uint32_t*)myP;

    const int rp0 = srp_w[0], rend = srp_w[dcount];
    int ld = 0;
    int nextb = srp_w[1];
    float racc0 = 0.0f, racc1 = 0.0f;

    for (int p = rp0; p < rend; p += 32) {
        const int cnt = (rend - p < 32) ? (rend - p) : 32;
        if (lane < 32) {
            uint32_t u = (lane < cnt) ? sesq[p + lane] : 0u;
            sse_w[lane]  = (float)(u >> 16) * (1.0f / 13107.0f);
            ssrc_w[lane] = (int)(u & 0xFFFFu);
        }
        __builtin_amdgcn_wave_barrier();

        #pragma unroll
        for (int mt = 0; mt < 2; ++mt) {
            if (mt * 16 >= cnt) break;          // wave-uniform

            // gaussian A fragments for this 16-edge tile (hi/lo of g)
            float ev = sse_w[mt * 16 + lrow];
            bf16x8 ah[2], al[2];
            #pragma unroll
            for (int ks = 0; ks < 2; ++ks) {
                #pragma unroll
                for (int j = 0; j < 8; ++j) {
                    int k = ks * 32 + lgrp * 8 + j;
                    float dd = ev - (5.0f / 63.0f) * (float)k;
                    float g = __expf(coeff * dd * dd);
                    __bf16 h = (__bf16)g;
                    ah[ks][j] = h;
                    al[ks][j] = (__bf16)(g - (float)h);
                }
            }

            // filter MFMA (2-term hi/lo of g x bf16 W)
            f32x4 c[8];
            #pragma unroll
            for (int nt = 0; nt < 8; ++nt) c[nt] = (f32x4){0.f, 0.f, 0.f, 0.f};
            #pragma unroll
            for (int ks = 0; ks < 2; ++ks) {
                #pragma unroll
                for (int nt = 0; nt < 8; ++nt) {
                    int n = nt * 16 + lrow;
                    int addr = n * 64 + (((ks * 4 + lgrp) ^ (n & 7)) << 3);
                    bf16x8 bh = *(const bf16x8*)&sWf[addr];
                    c[nt] = __builtin_amdgcn_mfma_f32_16x16x32_bf16(ah[ks], bh, c[nt], 0, 0, 0);
                    c[nt] = __builtin_amdgcn_mfma_f32_16x16x32_bf16(al[ks], bh, c[nt], 0, 0, 0);
                }
            }

            // bounce: bias + bf16 pack into wave-private LDS
            #pragma unroll
            for (int nt = 0; nt < 8; ++nt) {
                int f = nt * 16 + lrow;
                #pragma unroll
                for (int r = 0; r < 4; ++r) {
                    int e2 = lgrp * 4 + r;
                    float v = c[nt][r] + bv[nt];
                    myP[e2 * 128 + (((f >> 3) ^ (e2 & 7)) << 3) + (f & 7)] = (__bf16)v;
                }
            }
            __builtin_amdgcn_wave_barrier();

            // fully-batched consume: 16 bf16-rf gathers + 16 LDS reads in flight
            uint32_t rw[16];
            uint32_t uu[16];
            #pragma unroll
            for (int j = 0; j < 16; ++j) {
                int src = ssrc_w[mt * 16 + j];
                rw[j] = rfb[(size_t)src * 64 + lane];
                uu[j] = myPu[j * 64 + (((lane >> 2) ^ (j & 7)) << 2) + (lane & 3)];
            }
            #pragma unroll
            for (int j = 0; j < 16; ++j) {
                int gj = p + mt * 16 + j;
                if (gj < rend) {                       // wave-uniform
                    while (gj >= nextb) {              // wave-uniform
                        float2 st; st.x = racc0; st.y = racc1;
                        *(float2*)&seg[(size_t)(d_start + ld) * 128 + lane * 2] = st;
                        racc0 = 0.0f; racc1 = 0.0f;
                        ++ld;
                        nextb = srp_w[ld + 1];
                    }
                    racc0 = fmaf(__uint_as_float(rw[j] << 16),
                                 __uint_as_float(uu[j] << 16), racc0);
                    racc1 = fmaf(__uint_as_float(rw[j] & 0xFFFF0000u),
                                 __uint_as_float(uu[j] & 0xFFFF0000u), racc1);
                }
            }
            __builtin_amdgcn_wave_barrier();           // before myP reuse
        }
    }
    // flush remaining dsts (incl. trailing empty ones)
    while (ld < dcount) {
        float2 st; st.x = racc0; st.y = racc1;
        *(float2*)&seg[(size_t)(d_start + ld) * 128 + lane * 2] = st;
        racc0 = 0.0f; racc1 = 0.0f;
        ++ld;
    }
}

// ---------------------------------------------------------------------------
// Fused Dense1+Dense2, in place over seg (=d_out). Per 64-row tile:
// MFMA-1 (seg@W1, 3-term hi/lo) -> +b1 -> ssp -> bf16 bounce (wave LDS, XOR
// granules) -> y-frags -> MFMA-2 (y @ W2 hi + y @ W2 lo) -> +b2 -> store.
// Row-local, so in-place is safe. Weights staged from packed arrays (copy).
// ---------------------------------------------------------------------------
__global__ __launch_bounds__(256) void dense12(float* __restrict__ io,
                                               const __bf16* __restrict__ pW1H,
                                               const __bf16* __restrict__ pW1L,
                                               const float* __restrict__ b1,
                                               const __bf16* __restrict__ pW2H,
                                               const __bf16* __restrict__ pW2L,
                                               const float* __restrict__ b2) {
    __shared__ __bf16 s1h[128 * 128];   // 32KB each
    __shared__ __bf16 s1l[128 * 128];
    __shared__ __bf16 s2h[128 * 128];
    __shared__ __bf16 s2l[128 * 128];
    __shared__ __bf16 sy[WPB][16 * 128];  // 4KB/wave y1 bounce

    const int tid = threadIdx.x;
    {
        const uint4* a = (const uint4*)pW1H;
        const uint4* b = (const uint4*)pW1L;
        const uint4* c = (const uint4*)pW2H;
        const uint4* d = (const uint4*)pW2L;
        uint4* A = (uint4*)s1h; uint4* B = (uint4*)s1l;
        uint4* C = (uint4*)s2h; uint4* D = (uint4*)s2l;
        for (int i = tid; i < 2048; i += 256) {
            A[i] = a[i]; B[i] = b[i]; C[i] = c[i]; D[i] = d[i];
        }
    }
    __syncthreads();

    const int lane = tid & 63, w = tid >> 6;
    const int lrow = lane & 15, lgrp = lane >> 4;

    float bv1[8], bv2[8];
    #pragma unroll
    for (int nt = 0; nt < 8; ++nt) {
        bv1[nt] = b1[nt * 16 + lrow];
        bv2[nt] = b2[nt * 16 + lrow];
    }
    __bf16* myY = sy[w];

    for (int base = blockIdx.x * 64; base < NA; base += gridDim.x * 64) {
        const int row  = base + w * 16 + lrow;
        const int rowc = row < NA ? row : NA - 1;

        // ---- stage 1: y1 = ssp(seg @ W1 + b1) ----
        f32x4 acc[8];
        #pragma unroll
        for (int nt = 0; nt < 8; ++nt) acc[nt] = (f32x4){0.f, 0.f, 0.f, 0.f};

        #pragma unroll
        for (int ks = 0; ks < 4; ++ks) {
            int k0 = ks * 32 + lgrp * 8;
            float4 f0 = *(const float4*)&io[(size_t)rowc * 128 + k0];
            float4 f1 = *(const float4*)&io[(size_t)rowc * 128 + k0 + 4];
            float av[8] = {f0.x, f0.y, f0.z, f0.w, f1.x, f1.y, f1.z, f1.w};
            bf16x8 ah, al;
            #pragma unroll
            for (int j = 0; j < 8; ++j) {
                __bf16 h = (__bf16)av[j];
                ah[j] = h;
                al[j] = (__bf16)(av[j] - (float)h);
            }
            #pragma unroll
            for (int nt = 0; nt < 8; ++nt) {
                int n = nt * 16 + lrow;
                int addr = n * 128 + (((ks * 4 + lgrp) ^ (n & 15)) << 3);
                bf16x8 bh = *(const bf16x8*)&s1h[addr];
                bf16x8 bl = *(const bf16x8*)&s1l[addr];
                acc[nt] = __builtin_amdgcn_mfma_f32_16x16x32_bf16(ah, bh, acc[nt], 0, 0, 0);
                acc[nt] = __builtin_amdgcn_mfma_f32_16x16x32_bf16(ah, bl, acc[nt], 0, 0, 0);
                acc[nt] = __builtin_amdgcn_mfma_f32_16x16x32_bf16(al, bh, acc[nt], 0, 0, 0);
            }
        }

        // ssp + bf16 bounce into wave-private LDS (XOR 16B granules)
        #pragma unroll
        for (int nt = 0; nt < 8; ++nt) {
            int f = nt * 16 + lrow;
            #pragma unroll
            for (int r = 0; r < 4; ++r) {
                int e2 = lgrp * 4 + r;
                float v = ssp(acc[nt][r] + bv1[nt]);
                myY[e2 * 128 + (((f >> 3) ^ (e2 & 7)) << 3) + (f & 7)] = (__bf16)v;
            }
        }
        __builtin_amdgcn_wave_barrier();

        // ---- stage 2: out = y1 @ W2 + b2 (y single bf16, W2 hi+lo) ----
        f32x4 acc2[8];
        #pragma unroll
        for (int nt = 0; nt < 8; ++nt) acc2[nt] = (f32x4){0.f, 0.f, 0.f, 0.f};

        #pragma unroll
        for (int ks = 0; ks < 4; ++ks) {
            int g = ks * 4 + lgrp;
            bf16x8 ya = *(const bf16x8*)&myY[lrow * 128 + ((g ^ (lrow & 7)) << 3)];
            #pragma unroll
            for (int nt = 0; nt < 8; ++nt) {
                int n = nt * 16 + lrow;
                int addr = n * 128 + ((g ^ (n & 15)) << 3);
                bf16x8 bh = *(const bf16x8*)&s2h[addr];
                bf16x8 bl = *(const bf16x8*)&s2l[addr];
                acc2[nt] = __builtin_amdgcn_mfma_f32_16x16x32_bf16(ya, bh, acc2[nt], 0, 0, 0);
                acc2[nt] = __builtin_amdgcn_mfma_f32_16x16x32_bf16(ya, bl, acc2[nt], 0, 0, 0);
            }
        }
        __builtin_amdgcn_wave_barrier();   // myY reads done before next tile

        const int orow = base + w * 16 + lgrp * 4;
        #pragma unroll
        for (int r = 0; r < 4; ++r) {
            if (orow + r < NA) {
                #pragma unroll
                for (int nt = 0; nt < 8; ++nt) {
                    io[(size_t)(orow + r) * 128 + nt * 16 + lrow] = acc2[nt][r] + bv2[nt];
                }
            }
        }
    }
}

extern "C" void kernel_launch(void* const* d_in, const int* in_sizes, int n_in,
                              void* d_out, int out_size, void* d_ws, size_t ws_size,
                              hipStream_t stream) {
    const float* r   = (const float*)d_in[0];
    const float* e   = (const float*)d_in[1];
    const float* Wf2 = (const float*)d_in[2];
    const float* bf2 = (const float*)d_in[3];
    const float* Wa  = (const float*)d_in[4];
    const float* W1  = (const float*)d_in[5];
    const float* b1  = (const float*)d_in[6];
    const float* W2  = (const float*)d_in[7];
    const float* b2  = (const float*)d_in[8];
    const int*   a   = (const int*)d_in[9];

    float* out = (float*)d_out;

    // workspace layout (4B words)
    uint32_t* rfb        = (uint32_t*)d_ws;              // rf bf16 (3.2M words)
    int*      counts     = (int*)d_ws + 6400000;         // NBIN
    int*      row_ptr    = counts + NBIN;                // NBIN
    int*      cursor     = row_ptr + NBIN;               // NBIN
    int*      chunk_sums = cursor + NBIN;                // 128
    uint32_t* sesq       = (uint32_t*)(chunk_sums + 128);// NE packed u16:u16
    __bf16*   pWaH       = (__bf16*)(sesq + NE);         // 6x16384 + 8192 bf16
    __bf16*   pWaL       = pWaH + 16384;
    __bf16*   pW1H       = pWaL + 16384;
    __bf16*   pW1L       = pW1H + 16384;
    __bf16*   pW2H       = pW1L + 16384;
    __bf16*   pW2L       = pW2H + 16384;
    __bf16*   pWf        = pW2L + 16384;

    float* seg = out;   // d_out doubles as segment-sum buffer (fully overwritten)

    hipMemsetAsync(counts, 0, NBIN * sizeof(int), stream);
    pack_weights<<<64, 256, 0, stream>>>(Wa, W1, W2, Wf2,
                                         pWaH, pWaL, pW1H, pW1L, pW2H, pW2L, pWf);

    // hist (atomic-bound) || rf-GEMM first half
    hist_rf<<<SCAT_BLKS + RF_BLKS, 256, 0, stream>>>(a, counts, r, pWaH, pWaL, rfb);
    scanA<<<NCH, 512, 0, stream>>>(counts, chunk_sums);
    scanB<<<1, 128, 0, stream>>>(chunk_sums);
    scanC<<<NCH, 512, 0, stream>>>(counts, chunk_sums, row_ptr, cursor);
    // scatter (latency-bound) || rf-GEMM second half
    scatter_rf<<<SCAT_BLKS + RF_BLKS, 256, 0, stream>>>(a, e, cursor, sesq,
                                                        r, pWaH, pWaL, rfb);

    // fused edge pipeline
    edge_fused<<<EGRID, 256, 0, stream>>>(sesq, row_ptr, pWf, bf2, rfb, seg);

    // fused Dense1+Dense2, in place over seg/d_out
    dense12<<<256, 256, 0, stream>>>(seg, pW1H, pW1L, b1, pW2H, pW2L, b2);
}